// Round 1
// baseline (567.644 us; speedup 1.0000x reference)
//
#include <hip/hip_runtime.h>
#include <stdint.h>

#define Bn 4
#define Tn 2048
#define Cn 1024
#define Hn 16
#define HSn 64
#define Mn (Bn*Tn)
#define N1n (3*Cn)

typedef unsigned short u16;
typedef unsigned int u32;
typedef __attribute__((ext_vector_type(8))) short short8;
typedef __attribute__((ext_vector_type(4))) float f32x4;

__device__ __forceinline__ u16 f2bf(float f){
  u32 u = __float_as_uint(f);
  u += 0x7fffu + ((u >> 16) & 1u);
  return (u16)(u >> 16);
}

__device__ __forceinline__ void gload_lds16(const void* g, void* l){
  __builtin_amdgcn_global_load_lds(
      (const __attribute__((address_space(1))) u32*)g,
      (__attribute__((address_space(3))) u32*)l, 16, 0, 0);
}

// ---------------- flat f32 -> bf16 convert ----------------
__global__ void k_cvt(const float* __restrict__ in, u16* __restrict__ out, int n8){
  int i = blockIdx.x*256 + threadIdx.x;
  if (i >= n8) return;
  const float4* p = (const float4*)(in) + (size_t)i*2;
  float4 a = p[0], b = p[1];
  uint4 r;
  r.x = (u32)f2bf(a.x) | ((u32)f2bf(a.y) << 16);
  r.y = (u32)f2bf(a.z) | ((u32)f2bf(a.w) << 16);
  r.z = (u32)f2bf(b.x) | ((u32)f2bf(b.y) << 16);
  r.w = (u32)f2bf(b.z) | ((u32)f2bf(b.w) << 16);
  *((uint4*)(out) + i) = r;
}

// ------- transpose + convert: in f32 [R][Cc] -> out bf16 [Cc][R] -------
__global__ void k_tcvt(const float* __restrict__ in, u16* __restrict__ out, int R, int Cc){
  __shared__ float sh[64][68];
  int tid = threadIdx.x;
  int c0 = blockIdx.x*64, r0 = blockIdx.y*64;
  int rr = tid >> 4, c4 = (tid & 15) * 4;
  #pragma unroll
  for (int p=0;p<4;p++){
    int r = rr + 16*p;
    *(float4*)&sh[r][c4] = *(const float4*)&in[(size_t)(r0+r)*Cc + c0 + c4];
  }
  __syncthreads();
  #pragma unroll
  for (int p=0;p<4;p++){
    int oc = rr + 16*p;
    u32 w0 = (u32)f2bf(sh[c4+0][oc]) | ((u32)f2bf(sh[c4+1][oc]) << 16);
    u32 w1 = (u32)f2bf(sh[c4+2][oc]) | ((u32)f2bf(sh[c4+3][oc]) << 16);
    uint2 pk; pk.x = w0; pk.y = w1;
    *(uint2*)&out[(size_t)(c0+oc)*R + r0 + c4] = pk;
  }
}

// ---------------- GEMM: C[m,n] = A[m,:] . Bt[n,:] + bias[n] ----------------
// A [M][K] bf16, Bt [N][K] bf16. 128x128 tile, BK=64, 4 waves (2x2), each 64x64.
template <int OUT_BF16>
__global__ __launch_bounds__(256, 2)
void k_gemm(const u16* __restrict__ A, const u16* __restrict__ Bt,
            const float* __restrict__ bias, void* __restrict__ Cout,
            int Nn_, int K)
{
  __shared__ __align__(16) u16 As[128*64];
  __shared__ __align__(16) u16 Bs[128*64];
  int tid = threadIdx.x;
  int wave = tid >> 6, lane = tid & 63, g = lane >> 4, cl = lane & 15;
  int wm = wave >> 1, wn = wave & 1;
  int m0 = blockIdx.y * 128, n0 = blockIdx.x * 128;
  f32x4 acc[4][4];
  #pragma unroll
  for (int i=0;i<4;i++)
    #pragma unroll
    for (int j=0;j<4;j++) acc[i][j] = (f32x4){0.f,0.f,0.f,0.f};
  int nkt = K >> 6;
  for (int kt=0; kt<nkt; ++kt){
    __syncthreads();
    #pragma unroll
    for (int i=0;i<4;i++){
      int off = i*4096 + tid*16;          // byte offset within 16KB tile
      int row = off >> 7, kb = off & 127; // 128B per LDS row (64 bf16)
      int lbase = i*4096 + (wave << 10);  // wave-uniform LDS base
      gload_lds16((const char*)A  + ((size_t)(m0+row)*K + ((size_t)kt<<6))*2 + kb,
                  (char*)As + lbase);
      gload_lds16((const char*)Bt + ((size_t)(n0+row)*K + ((size_t)kt<<6))*2 + kb,
                  (char*)Bs + lbase);
    }
    __syncthreads();
    #pragma unroll
    for (int kk=0; kk<2; ++kk){
      short8 a[4], b[4];
      #pragma unroll
      for (int i=0;i<4;i++)
        a[i] = *(const short8*)&As[(wm*64 + i*16 + cl)*64 + kk*32 + g*8];
      #pragma unroll
      for (int j=0;j<4;j++)
        b[j] = *(const short8*)&Bs[(wn*64 + j*16 + cl)*64 + kk*32 + g*8];
      #pragma unroll
      for (int i=0;i<4;i++)
        #pragma unroll
        for (int j=0;j<4;j++)
          acc[i][j] = __builtin_amdgcn_mfma_f32_16x16x32_bf16(a[i], b[j], acc[i][j], 0, 0, 0);
    }
  }
  // epilogue: D frag layout col=lane&15, row=4*(lane>>4)+reg
  #pragma unroll
  for (int j=0;j<4;j++){
    int col = n0 + wn*64 + j*16 + cl;
    float bj = bias[col];
    #pragma unroll
    for (int i=0;i<4;i++){
      int rowb = m0 + wm*64 + i*16 + g*4;
      #pragma unroll
      for (int r=0;r<4;r++){
        float v = acc[i][j][r] + bj;
        if (OUT_BF16) ((u16*)Cout)[(size_t)(rowb+r)*Nn_ + col] = f2bf(v);
        else          ((float*)Cout)[(size_t)(rowb+r)*Nn_ + col] = v;
      }
    }
  }
}

// ------- V transpose: qkv v-part -> Vt[bh][d][t] (bf16) -------
__global__ void k_tv(const u16* __restrict__ qkv, u16* __restrict__ vt){
  __shared__ __align__(16) u16 sh[64][80];
  int tid = threadIdx.x;
  int tt = blockIdx.x * 64, bh = blockIdx.y;
  int b = bh >> 4, h = bh & 15;
  const u16* src = qkv + (size_t)(b*Tn + tt)*N1n + 2*Cn + h*HSn;
  int r = tid >> 3, c8 = (tid & 7) * 8;
  #pragma unroll
  for (int p=0;p<2;p++){
    int rr2 = r + 32*p;
    *(uint4*)&sh[rr2][c8] = *(const uint4*)&src[(size_t)rr2*N1n + c8];
  }
  __syncthreads();
  u16* dst = vt + (size_t)bh*HSn*Tn + tt;
  #pragma unroll
  for (int p=0;p<2;p++){
    int d = r + 32*p;
    u32 w0 = (u32)sh[c8+0][d] | ((u32)sh[c8+1][d] << 16);
    u32 w1 = (u32)sh[c8+2][d] | ((u32)sh[c8+3][d] << 16);
    u32 w2 = (u32)sh[c8+4][d] | ((u32)sh[c8+5][d] << 16);
    u32 w3 = (u32)sh[c8+6][d] | ((u32)sh[c8+7][d] << 16);
    uint4 pk; pk.x=w0; pk.y=w1; pk.z=w2; pk.w=w3;
    *(uint4*)&dst[(size_t)d*Tn + c8] = pk;
  }
}

// ---------------- causal flash attention ----------------
// grid (T/64, B*H); 4 waves x 16 q-rows; KV tiles of 64.
__global__ __launch_bounds__(256, 2)
void k_attn(const u16* __restrict__ qkv, const u16* __restrict__ vt, u16* __restrict__ yb){
  __shared__ __align__(16) u16 Plds[4][16*80];
  int tid = threadIdx.x, wave = tid >> 6, lane = tid & 63, g = lane >> 4, cl = lane & 15;
  int q0 = blockIdx.x * 64, bh = blockIdx.y, b = bh >> 4, h = bh & 15;
  const u16* Qp = qkv + (size_t)(b*Tn + q0 + wave*16)*N1n + h*HSn;
  const u16* Kp = qkv + (size_t)(b*Tn)*N1n + Cn + h*HSn;
  const u16* Vp = vt + (size_t)bh*HSn*Tn;
  short8 qf0 = *(const short8*)&Qp[(size_t)cl*N1n + g*8];
  short8 qf1 = *(const short8*)&Qp[(size_t)cl*N1n + 32 + g*8];
  f32x4 o[4];
  #pragma unroll
  for (int db=0;db<4;db++) o[db] = (f32x4){0.f,0.f,0.f,0.f};
  float m[4], l[4];
  #pragma unroll
  for (int r=0;r<4;r++){ m[r] = -1e30f; l[r] = 0.f; }
  int ntiles = blockIdx.x + 1;
  int qrow = q0 + wave*16 + g*4;   // +r
  for (int kt=0; kt<ntiles; ++kt){
    int kb = kt*64;
    f32x4 s[4];
    #pragma unroll
    for (int bs=0;bs<4;bs++){
      const u16* kp = Kp + (size_t)(kb + bs*16 + cl)*N1n + g*8;
      short8 k0 = *(const short8*)kp;
      short8 k1 = *(const short8*)(kp + 32);
      f32x4 t = (f32x4){0.f,0.f,0.f,0.f};
      t = __builtin_amdgcn_mfma_f32_16x16x32_bf16(qf0, k0, t, 0, 0, 0);
      t = __builtin_amdgcn_mfma_f32_16x16x32_bf16(qf1, k1, t, 0, 0, 0);
      s[bs] = t;
    }
    if (kt == ntiles-1){
      #pragma unroll
      for (int bs=0;bs<4;bs++){
        int kcol = kb + bs*16 + cl;
        #pragma unroll
        for (int r=0;r<4;r++){
          float v = s[bs][r]*0.125f;
          s[bs][r] = (kcol > qrow + r) ? -1e30f : v;
        }
      }
    } else {
      #pragma unroll
      for (int bs=0;bs<4;bs++)
        #pragma unroll
        for (int r=0;r<4;r++) s[bs][r] *= 0.125f;
    }
    // online softmax (rows live in 4 regs; cols across 16-lane group)
    float mt[4], mn[4], al[4], ls[4];
    #pragma unroll
    for (int r=0;r<4;r++)
      mt[r] = fmaxf(fmaxf(s[0][r], s[1][r]), fmaxf(s[2][r], s[3][r]));
    #pragma unroll
    for (int sh=1; sh<16; sh<<=1)
      #pragma unroll
      for (int r=0;r<4;r++) mt[r] = fmaxf(mt[r], __shfl_xor(mt[r], sh, 64));
    #pragma unroll
    for (int r=0;r<4;r++){
      mn[r] = fmaxf(m[r], mt[r]);
      al[r] = __expf(m[r] - mn[r]);
      m[r] = mn[r];
      ls[r] = 0.f;
    }
    #pragma unroll
    for (int bs=0;bs<4;bs++)
      #pragma unroll
      for (int r=0;r<4;r++){
        float p = __expf(s[bs][r] - mn[r]);
        s[bs][r] = p; ls[r] += p;
      }
    #pragma unroll
    for (int r=0;r<4;r++) l[r] = l[r]*al[r] + ls[r];   // lane-partial; reduced at end
    #pragma unroll
    for (int db=0;db<4;db++)
      #pragma unroll
      for (int r=0;r<4;r++) o[db][r] *= al[r];
    // P (D-layout) -> LDS -> A-layout fragments
    u16* pl = &Plds[wave][0];
    #pragma unroll
    for (int bs=0;bs<4;bs++)
      #pragma unroll
      for (int r=0;r<4;r++)
        pl[(g*4+r)*80 + bs*16 + cl] = f2bf(s[bs][r]);
    asm volatile("s_waitcnt lgkmcnt(0)" ::: "memory");
    short8 pf0 = *(const short8*)&pl[cl*80 + g*8];
    short8 pf1 = *(const short8*)&pl[cl*80 + 32 + g*8];
    #pragma unroll
    for (int db=0;db<4;db++){
      const u16* vp = Vp + (size_t)(db*16 + cl)*Tn + kb + g*8;
      short8 v0 = *(const short8*)vp;
      short8 v1 = *(const short8*)(vp + 32);
      o[db] = __builtin_amdgcn_mfma_f32_16x16x32_bf16(pf0, v0, o[db], 0, 0, 0);
      o[db] = __builtin_amdgcn_mfma_f32_16x16x32_bf16(pf1, v1, o[db], 0, 0, 0);
    }
  }
  // final row-sum reduce + normalize + store
  #pragma unroll
  for (int sh=1; sh<16; sh<<=1)
    #pragma unroll
    for (int r=0;r<4;r++) l[r] += __shfl_xor(l[r], sh, 64);
  u16* yp = yb + (size_t)(b*Tn + q0 + wave*16)*Cn + h*HSn;
  #pragma unroll
  for (int db=0;db<4;db++)
    #pragma unroll
    for (int r=0;r<4;r++){
      float vv = o[db][r] / l[r];
      yp[(size_t)(g*4+r)*Cn + db*16 + cl] = f2bf(vv);
    }
}

extern "C" void kernel_launch(void* const* d_in, const int* in_sizes, int n_in,
                              void* d_out, int out_size, void* d_ws, size_t ws_size,
                              hipStream_t stream)
{
  const float* x      = (const float*)d_in[0];
  const float* w_attn = (const float*)d_in[1];
  const float* b_attn = (const float*)d_in[2];
  const float* w_proj = (const float*)d_in[3];
  const float* b_proj = (const float*)d_in[4];
  float* out = (float*)d_out;
  char* ws = (char*)d_ws;

  size_t off = 0;
  u16* xb  = (u16*)(ws + off); off += (size_t)Mn*Cn*2;        // 16.8 MB
  u16* waT = (u16*)(ws + off); off += (size_t)N1n*Cn*2;       //  6.3 MB
  u16* wpT = (u16*)(ws + off); off += (size_t)Cn*Cn*2;        //  2.1 MB
  u16* qkv = (u16*)(ws + off); off += (size_t)Mn*N1n*2;       // 50.3 MB
  u16* vt  = (u16*)(ws + off); off += (size_t)Bn*Hn*HSn*Tn*2; // 16.8 MB
  u16* yb  = (u16*)(ws + off); off += (size_t)Mn*Cn*2;        // 16.8 MB
  // total ~109 MB of d_ws

  k_cvt<<<dim3(Mn*Cn/8/256), 256, 0, stream>>>(x, xb, Mn*Cn/8);
  k_tcvt<<<dim3(N1n/64, Cn/64), 256, 0, stream>>>(w_attn, waT, Cn, N1n);
  k_tcvt<<<dim3(Cn/64, Cn/64), 256, 0, stream>>>(w_proj, wpT, Cn, Cn);
  k_gemm<1><<<dim3(N1n/128, Mn/128), 256, 0, stream>>>(xb, waT, b_attn, qkv, N1n, Cn);
  k_tv<<<dim3(Tn/64, Bn*Hn), 256, 0, stream>>>(qkv, vt);
  k_attn<<<dim3(Tn/64, Bn*Hn), 256, 0, stream>>>(qkv, vt, yb);
  k_gemm<0><<<dim3(Cn/128, Mn/128), 256, 0, stream>>>(yb, wpT, b_proj, out, Cn, Cn);
}

// Round 2
// 232.949 us; speedup vs baseline: 2.4368x; 2.4368x over previous
//
#include <hip/hip_runtime.h>
#include <stdint.h>

#define Bn 4
#define Tn 2048
#define Cn 1024
#define Hn 16
#define HSn 64
#define Mn (Bn*Tn)
#define N1n (3*Cn)

typedef unsigned short u16;
typedef unsigned int u32;
typedef __attribute__((ext_vector_type(8))) short short8;
typedef __attribute__((ext_vector_type(4))) float f32x4;
typedef __attribute__((ext_vector_type(16))) float f32x16;

__device__ __forceinline__ u16 f2bf(float f){
  u32 u = __float_as_uint(f);
  u += 0x7fffu + ((u >> 16) & 1u);
  return (u16)(u >> 16);
}

__device__ __forceinline__ u32 pkbf(float lo, float hi_){
  u32 r; asm("v_cvt_pk_bf16_f32 %0, %1, %2" : "=v"(r) : "v"(lo), "v"(hi_)); return r;
}

__device__ __forceinline__ void gload_lds16(const void* g, void* l){
  __builtin_amdgcn_global_load_lds(
      (const __attribute__((address_space(1))) u32*)g,
      (__attribute__((address_space(3))) u32*)l, 16, 0, 0);
}

// ---------------- flat f32 -> bf16 convert ----------------
__global__ void k_cvt(const float* __restrict__ in, u16* __restrict__ out, int n8){
  int i = blockIdx.x*256 + threadIdx.x;
  if (i >= n8) return;
  const float4* p = (const float4*)(in) + (size_t)i*2;
  float4 a = p[0], b = p[1];
  uint4 r;
  r.x = (u32)f2bf(a.x) | ((u32)f2bf(a.y) << 16);
  r.y = (u32)f2bf(a.z) | ((u32)f2bf(a.w) << 16);
  r.z = (u32)f2bf(b.x) | ((u32)f2bf(b.y) << 16);
  r.w = (u32)f2bf(b.z) | ((u32)f2bf(b.w) << 16);
  *((uint4*)(out) + i) = r;
}

// ------- transpose + convert: in f32 [R][Cc] -> out bf16 [Cc][R] -------
__global__ void k_tcvt(const float* __restrict__ in, u16* __restrict__ out, int R, int Cc){
  __shared__ float sh[64][68];
  int tid = threadIdx.x;
  int c0 = blockIdx.x*64, r0 = blockIdx.y*64;
  int rr = tid >> 4, c4 = (tid & 15) * 4;
  #pragma unroll
  for (int p=0;p<4;p++){
    int r = rr + 16*p;
    *(float4*)&sh[r][c4] = *(const float4*)&in[(size_t)(r0+r)*Cc + c0 + c4];
  }
  __syncthreads();
  #pragma unroll
  for (int p=0;p<4;p++){
    int oc = rr + 16*p;
    u32 w0 = (u32)f2bf(sh[c4+0][oc]) | ((u32)f2bf(sh[c4+1][oc]) << 16);
    u32 w1 = (u32)f2bf(sh[c4+2][oc]) | ((u32)f2bf(sh[c4+3][oc]) << 16);
    uint2 pk; pk.x = w0; pk.y = w1;
    *(uint2*)&out[(size_t)(c0+oc)*R + r0 + c4] = pk;
  }
}

// ---------------- GEMM: C[m,n] = A[m,:] . Bt[n,:] + bias[n] ----------------
template <int OUT_BF16>
__global__ __launch_bounds__(256, 2)
void k_gemm(const u16* __restrict__ A, const u16* __restrict__ Bt,
            const float* __restrict__ bias, void* __restrict__ Cout,
            int Nn_, int K)
{
  __shared__ __align__(16) u16 As[128*64];
  __shared__ __align__(16) u16 Bs[128*64];
  int tid = threadIdx.x;
  int wave = tid >> 6, lane = tid & 63, g = lane >> 4, cl = lane & 15;
  int wm = wave >> 1, wn = wave & 1;
  int m0 = blockIdx.y * 128, n0 = blockIdx.x * 128;
  f32x4 acc[4][4];
  #pragma unroll
  for (int i=0;i<4;i++)
    #pragma unroll
    for (int j=0;j<4;j++) acc[i][j] = (f32x4){0.f,0.f,0.f,0.f};
  int nkt = K >> 6;
  for (int kt=0; kt<nkt; ++kt){
    __syncthreads();
    #pragma unroll
    for (int i=0;i<4;i++){
      int off = i*4096 + tid*16;
      int row = off >> 7, kb = off & 127;
      int lbase = i*4096 + (wave << 10);
      gload_lds16((const char*)A  + ((size_t)(m0+row)*K + ((size_t)kt<<6))*2 + kb,
                  (char*)As + lbase);
      gload_lds16((const char*)Bt + ((size_t)(n0+row)*K + ((size_t)kt<<6))*2 + kb,
                  (char*)Bs + lbase);
    }
    __syncthreads();
    #pragma unroll
    for (int kk=0; kk<2; ++kk){
      short8 a[4], b[4];
      #pragma unroll
      for (int i=0;i<4;i++)
        a[i] = *(const short8*)&As[(wm*64 + i*16 + cl)*64 + kk*32 + g*8];
      #pragma unroll
      for (int j=0;j<4;j++)
        b[j] = *(const short8*)&Bs[(wn*64 + j*16 + cl)*64 + kk*32 + g*8];
      #pragma unroll
      for (int i=0;i<4;i++)
        #pragma unroll
        for (int j=0;j<4;j++)
          acc[i][j] = __builtin_amdgcn_mfma_f32_16x16x32_bf16(a[i], b[j], acc[i][j], 0, 0, 0);
    }
  }
  #pragma unroll
  for (int j=0;j<4;j++){
    int col = n0 + wn*64 + j*16 + cl;
    float bj = bias[col];
    #pragma unroll
    for (int i=0;i<4;i++){
      int rowb = m0 + wm*64 + i*16 + g*4;
      #pragma unroll
      for (int r=0;r<4;r++){
        float v = acc[i][j][r] + bj;
        if (OUT_BF16) ((u16*)Cout)[(size_t)(rowb+r)*Nn_ + col] = f2bf(v);
        else          ((float*)Cout)[(size_t)(rowb+r)*Nn_ + col] = v;
      }
    }
  }
}

// ------- V transpose: qkv v-part -> Vt[bh][d][t] (bf16) -------
__global__ void k_tv(const u16* __restrict__ qkv, u16* __restrict__ vt){
  __shared__ __align__(16) u16 sh[64][80];
  int tid = threadIdx.x;
  int tt = blockIdx.x * 64, bh = blockIdx.y;
  int b = bh >> 4, h = bh & 15;
  const u16* src = qkv + (size_t)(b*Tn + tt)*N1n + 2*Cn + h*HSn;
  int r = tid >> 3, c8 = (tid & 7) * 8;
  #pragma unroll
  for (int p=0;p<2;p++){
    int rr2 = r + 32*p;
    *(uint4*)&sh[rr2][c8] = *(const uint4*)&src[(size_t)rr2*N1n + c8];
  }
  __syncthreads();
  u16* dst = vt + (size_t)bh*HSn*Tn + tt;
  #pragma unroll
  for (int p=0;p<2;p++){
    int d = r + 32*p;
    u32 w0 = (u32)sh[c8+0][d] | ((u32)sh[c8+1][d] << 16);
    u32 w1 = (u32)sh[c8+2][d] | ((u32)sh[c8+3][d] << 16);
    u32 w2 = (u32)sh[c8+4][d] | ((u32)sh[c8+5][d] << 16);
    u32 w3 = (u32)sh[c8+6][d] | ((u32)sh[c8+7][d] << 16);
    uint4 pk; pk.x=w0; pk.y=w1; pk.z=w2; pk.w=w3;
    *(uint4*)&dst[(size_t)d*Tn + c8] = pk;
  }
}

// ---------------- causal flash attention, 32x32 swapped-QK^T ----------------
// grid (T/128, B*H); 4 waves x 32 q-rows; KV tiles of 64, double-buffered LDS.
// S^T = mfma(K,Q): lane holds S[k_rows][q=lane&31]; softmax in-register.
__global__ __launch_bounds__(256, 2)
void k_attn(const u16* __restrict__ qkv, const u16* __restrict__ vt, u16* __restrict__ yb){
  // K tile: [64 krow][64 d] bf16, row=128B, XOR-swizzled: byte ^= (row&7)<<4
  // V tile: [64 d][64 t] bf16, same swizzle
  __shared__ __align__(16) u16 Ks[2][64*64];
  __shared__ __align__(16) u16 Vs[2][64*64];
  int tid = threadIdx.x, wave = tid >> 6, lane = tid & 63;
  int ql = lane & 31, hi = lane >> 5;
  int q0 = blockIdx.x * 128, bh = blockIdx.y, b = bh >> 4, h = bh & 15;
  int qw0 = q0 + wave*32;
  int qg = qw0 + ql;

  const u16* Kbase = qkv + (size_t)b*Tn*N1n + Cn + h*HSn;
  const u16* Vbase = vt  + (size_t)bh*HSn*Tn;

  // Q B-frags (col=q=lane&31, k=d = dc*16 + hi*8 + j)
  const u16* Qp = qkv + (size_t)(b*Tn + qg)*N1n + h*HSn;
  short8 qf[4];
  #pragma unroll
  for (int dc=0; dc<4; ++dc) qf[dc] = *(const short8*)&Qp[dc*16 + hi*8];

  f32x16 accO[2];
  #pragma unroll
  for (int f=0; f<2; ++f)
    #pragma unroll
    for (int r=0; r<16; ++r) accO[f][r] = 0.f;
  float m_ = -1e30f, l_ = 0.f;

  auto STAGE = [&](int bufi, int kt){
    int kb_ = kt*64;
    #pragma unroll
    for (int it=0; it<2; ++it){
      int off = it*4096 + tid*16;
      int row = off >> 7;
      int cb  = off & 127;
      int gc  = (cb ^ ((row & 7) << 4)) >> 1;   // pre-swizzled source column
      gload_lds16(Kbase + (size_t)(kb_ + row)*N1n + gc,
                  (char*)&Ks[bufi][0] + it*4096 + (wave << 10));
      gload_lds16(Vbase + (size_t)row*Tn + kb_ + gc,
                  (char*)&Vs[bufi][0] + it*4096 + (wave << 10));
    }
  };

  int ntiles = blockIdx.x*2 + 2;
  STAGE(0, 0);
  asm volatile("s_waitcnt vmcnt(0)" ::: "memory");
  __syncthreads();
  int buf = 0;

  for (int kt=0; kt<ntiles; ++kt){
    if (kt+1 < ntiles) STAGE(buf^1, kt+1);
    const char* Ksb = (const char*)&Ks[buf][0];
    const char* Vsb = (const char*)&Vs[buf][0];
    #pragma unroll
    for (int ksub=0; ksub<2; ++ksub){
      int kbase = kt*64 + ksub*32;
      if (kbase <= qw0 + 31){
        // ---- QK^T (swapped): S^T[k][q] ----
        f32x16 s;
        #pragma unroll
        for (int r=0; r<16; ++r) s[r] = 0.f;
        #pragma unroll
        for (int dc=0; dc<4; ++dc){
          short8 kf = *(const short8*)(Ksb + ((ksub*32 + ql) << 7)
                          + ((dc*32 + hi*16) ^ ((ql & 7) << 4)));
          s = __builtin_amdgcn_mfma_f32_32x32x16_bf16(kf, qf[dc], s, 0, 0, 0);
        }
        // ---- scale + causal mask (k row = (r&3)+8*(r>>2)+4*hi) ----
        bool needmask = (kbase + 31 > qw0);
        float p[16];
        #pragma unroll
        for (int r=0; r<16; ++r){
          int krow = kbase + (r&3) + 8*(r>>2) + 4*hi;
          float v = s[r] * 0.125f;
          p[r] = (needmask && (krow > qg)) ? -1e30f : v;
        }
        // ---- row max: in-lane + pair exchange ----
        float tm = p[0];
        #pragma unroll
        for (int r=1; r<16; ++r) tm = fmaxf(tm, p[r]);
        tm = fmaxf(tm, __shfl_xor(tm, 32));
        // ---- defer-max rescale (THR=8) ----
        if (!__all(tm - m_ <= 8.0f)){
          float mn = fmaxf(m_, tm);
          float al = __expf(m_ - mn);
          m_ = mn; l_ *= al;
          #pragma unroll
          for (int f=0; f<2; ++f)
            #pragma unroll
            for (int r=0; r<16; ++r) accO[f][r] *= al;
        }
        float ls = 0.f;
        #pragma unroll
        for (int r=0; r<16; ++r){ float e = __expf(p[r] - m_); p[r] = e; ls += e; }
        l_ += ls + __shfl_xor(ls, 32);
        // ---- P -> bf16 B-frags (2 K-slices of 16) + PV ----
        #pragma unroll
        for (int ks=0; ks<2; ++ks){
          int pb = ks*8;
          u32 a0  = pkbf(p[pb+0], p[pb+1]);   // lo:kk(0,1)  hi:kk(4,5)
          u32 a1  = pkbf(p[pb+2], p[pb+3]);   // lo:kk(2,3)  hi:kk(6,7)
          u32 b0w = pkbf(p[pb+4], p[pb+5]);   // lo:kk(8,9)  hi:kk(12,13)
          u32 b1w = pkbf(p[pb+6], p[pb+7]);   // lo:kk(10,11) hi:kk(14,15)
          u32 a0x = (u32)__shfl_xor((int)a0, 32);
          u32 a1x = (u32)__shfl_xor((int)a1, 32);
          u32 b0x = (u32)__shfl_xor((int)b0w, 32);
          u32 b1x = (u32)__shfl_xor((int)b1w, 32);
          union { u32 w[4]; short8 v; } pu;
          pu.w[0] = hi ? b0x : a0;    // kk(hi*8+0, +1)
          pu.w[1] = hi ? b1x : a1;    // kk(hi*8+2, +3)
          pu.w[2] = hi ? b0w : a0x;   // kk(hi*8+4, +5)
          pu.w[3] = hi ? b1w : a1x;   // kk(hi*8+6, +7)
          #pragma unroll
          for (int f=0; f<2; ++f){
            short8 vf = *(const short8*)(Vsb + ((f*32 + ql) << 7)
                            + ((ksub*64 + ks*32 + hi*16) ^ ((ql & 7) << 4)));
            accO[f] = __builtin_amdgcn_mfma_f32_32x32x16_bf16(vf, pu.v, accO[f], 0, 0, 0);
          }
        }
      }
    }
    asm volatile("s_waitcnt vmcnt(0)" ::: "memory");
    __syncthreads();
    buf ^= 1;
  }

  // ---- epilogue: O^T[d][q] -> yb[q][d], normalize by l ----
  float rl = 1.0f / l_;
  u16* yp = yb + (size_t)(b*Tn + qg)*Cn + h*HSn;
  #pragma unroll
  for (int f=0; f<2; ++f)
    #pragma unroll
    for (int rq=0; rq<4; ++rq){
      int d0 = f*32 + rq*8 + hi*4;
      float v0 = accO[f][rq*4+0]*rl, v1 = accO[f][rq*4+1]*rl;
      float v2 = accO[f][rq*4+2]*rl, v3 = accO[f][rq*4+3]*rl;
      uint2 pk2;
      pk2.x = (u32)f2bf(v0) | ((u32)f2bf(v1) << 16);
      pk2.y = (u32)f2bf(v2) | ((u32)f2bf(v3) << 16);
      *(uint2*)&yp[d0] = pk2;
    }
}

extern "C" void kernel_launch(void* const* d_in, const int* in_sizes, int n_in,
                              void* d_out, int out_size, void* d_ws, size_t ws_size,
                              hipStream_t stream)
{
  const float* x      = (const float*)d_in[0];
  const float* w_attn = (const float*)d_in[1];
  const float* b_attn = (const float*)d_in[2];
  const float* w_proj = (const float*)d_in[3];
  const float* b_proj = (const float*)d_in[4];
  float* out = (float*)d_out;
  char* ws = (char*)d_ws;

  size_t off = 0;
  u16* xb  = (u16*)(ws + off); off += (size_t)Mn*Cn*2;
  u16* waT = (u16*)(ws + off); off += (size_t)N1n*Cn*2;
  u16* wpT = (u16*)(ws + off); off += (size_t)Cn*Cn*2;
  u16* qkv = (u16*)(ws + off); off += (size_t)Mn*N1n*2;
  u16* vt  = (u16*)(ws + off); off += (size_t)Bn*Hn*HSn*Tn*2;
  u16* yb  = (u16*)(ws + off); off += (size_t)Mn*Cn*2;

  k_cvt<<<dim3(Mn*Cn/8/256), 256, 0, stream>>>(x, xb, Mn*Cn/8);
  k_tcvt<<<dim3(N1n/64, Cn/64), 256, 0, stream>>>(w_attn, waT, Cn, N1n);
  k_tcvt<<<dim3(Cn/64, Cn/64), 256, 0, stream>>>(w_proj, wpT, Cn, Cn);
  k_gemm<1><<<dim3(N1n/128, Mn/128), 256, 0, stream>>>(xb, waT, b_attn, qkv, N1n, Cn);
  k_tv<<<dim3(Tn/64, Bn*Hn), 256, 0, stream>>>(qkv, vt);
  k_attn<<<dim3(Tn/128, Bn*Hn), 256, 0, stream>>>(qkv, vt, yb);
  k_gemm<0><<<dim3(Cn/128, Mn/128), 256, 0, stream>>>(yb, wpT, b_proj, out, Cn, Cn);
}

// Round 3
// 188.326 us; speedup vs baseline: 3.0142x; 1.2369x over previous
//
#include <hip/hip_runtime.h>
#include <stdint.h>

#define Bn 4
#define Tn 2048
#define Cn 1024
#define Hn 16
#define HSn 64
#define Mn (Bn*Tn)
#define N1n (3*Cn)

typedef unsigned short u16;
typedef unsigned int u32;
typedef __attribute__((ext_vector_type(8))) short short8;
typedef __attribute__((ext_vector_type(4))) float f32x4;
typedef __attribute__((ext_vector_type(16))) float f32x16;

__device__ __forceinline__ u16 f2bf(float f){
  u32 u = __float_as_uint(f);
  u += 0x7fffu + ((u >> 16) & 1u);
  return (u16)(u >> 16);
}

__device__ __forceinline__ u32 pkbf(float lo, float hi_){
  u32 r; asm("v_cvt_pk_bf16_f32 %0, %1, %2" : "=v"(r) : "v"(lo), "v"(hi_)); return r;
}

__device__ __forceinline__ float fexp2(float x){
#if __has_builtin(__builtin_amdgcn_exp2f)
  return __builtin_amdgcn_exp2f(x);
#else
  float r; asm("v_exp_f32 %0, %1" : "=v"(r) : "v"(x)); return r;
#endif
}

__device__ __forceinline__ void gload_lds16(const void* g, void* l){
  __builtin_amdgcn_global_load_lds(
      (const __attribute__((address_space(1))) u32*)g,
      (__attribute__((address_space(3))) u32*)l, 16, 0, 0);
}

// ---------------- flat f32 -> bf16 convert ----------------
__global__ void k_cvt(const float* __restrict__ in, u16* __restrict__ out, int n8){
  int i = blockIdx.x*256 + threadIdx.x;
  if (i >= n8) return;
  const float4* p = (const float4*)(in) + (size_t)i*2;
  float4 a = p[0], b = p[1];
  uint4 r;
  r.x = (u32)f2bf(a.x) | ((u32)f2bf(a.y) << 16);
  r.y = (u32)f2bf(a.z) | ((u32)f2bf(a.w) << 16);
  r.z = (u32)f2bf(b.x) | ((u32)f2bf(b.y) << 16);
  r.w = (u32)f2bf(b.z) | ((u32)f2bf(b.w) << 16);
  *((uint4*)(out) + i) = r;
}

// ------- transpose + convert: in f32 [R][Cc] -> out bf16 [Cc][R] -------
__global__ void k_tcvt(const float* __restrict__ in, u16* __restrict__ out, int R, int Cc){
  __shared__ float sh[64][68];
  int tid = threadIdx.x;
  int c0 = blockIdx.x*64, r0 = blockIdx.y*64;
  int rr = tid >> 4, c4 = (tid & 15) * 4;
  #pragma unroll
  for (int p=0;p<4;p++){
    int r = rr + 16*p;
    *(float4*)&sh[r][c4] = *(const float4*)&in[(size_t)(r0+r)*Cc + c0 + c4];
  }
  __syncthreads();
  #pragma unroll
  for (int p=0;p<4;p++){
    int oc = rr + 16*p;
    u32 w0 = (u32)f2bf(sh[c4+0][oc]) | ((u32)f2bf(sh[c4+1][oc]) << 16);
    u32 w1 = (u32)f2bf(sh[c4+2][oc]) | ((u32)f2bf(sh[c4+3][oc]) << 16);
    uint2 pk; pk.x = w0; pk.y = w1;
    *(uint2*)&out[(size_t)(c0+oc)*R + r0 + c4] = pk;
  }
}

// ---------------- GEMM: C[m,n] = A[m,:] . Bt[n,:] + bias[n] ----------------
template <int OUT_BF16>
__global__ __launch_bounds__(256, 2)
void k_gemm(const u16* __restrict__ A, const u16* __restrict__ Bt,
            const float* __restrict__ bias, void* __restrict__ Cout,
            int Nn_, int K)
{
  __shared__ __align__(16) u16 As[128*64];
  __shared__ __align__(16) u16 Bs[128*64];
  int tid = threadIdx.x;
  int wave = tid >> 6, lane = tid & 63, g = lane >> 4, cl = lane & 15;
  int wm = wave >> 1, wn = wave & 1;
  int m0 = blockIdx.y * 128, n0 = blockIdx.x * 128;
  f32x4 acc[4][4];
  #pragma unroll
  for (int i=0;i<4;i++)
    #pragma unroll
    for (int j=0;j<4;j++) acc[i][j] = (f32x4){0.f,0.f,0.f,0.f};
  int nkt = K >> 6;
  for (int kt=0; kt<nkt; ++kt){
    __syncthreads();
    #pragma unroll
    for (int i=0;i<4;i++){
      int off = i*4096 + tid*16;
      int row = off >> 7, kb = off & 127;
      int lbase = i*4096 + (wave << 10);
      gload_lds16((const char*)A  + ((size_t)(m0+row)*K + ((size_t)kt<<6))*2 + kb,
                  (char*)As + lbase);
      gload_lds16((const char*)Bt + ((size_t)(n0+row)*K + ((size_t)kt<<6))*2 + kb,
                  (char*)Bs + lbase);
    }
    __syncthreads();
    #pragma unroll
    for (int kk=0; kk<2; ++kk){
      short8 a[4], b[4];
      #pragma unroll
      for (int i=0;i<4;i++)
        a[i] = *(const short8*)&As[(wm*64 + i*16 + cl)*64 + kk*32 + g*8];
      #pragma unroll
      for (int j=0;j<4;j++)
        b[j] = *(const short8*)&Bs[(wn*64 + j*16 + cl)*64 + kk*32 + g*8];
      #pragma unroll
      for (int i=0;i<4;i++)
        #pragma unroll
        for (int j=0;j<4;j++)
          acc[i][j] = __builtin_amdgcn_mfma_f32_16x16x32_bf16(a[i], b[j], acc[i][j], 0, 0, 0);
    }
  }
  #pragma unroll
  for (int j=0;j<4;j++){
    int col = n0 + wn*64 + j*16 + cl;
    float bj = bias[col];
    #pragma unroll
    for (int i=0;i<4;i++){
      int rowb = m0 + wm*64 + i*16 + g*4;
      #pragma unroll
      for (int r=0;r<4;r++){
        float v = acc[i][j][r] + bj;
        if (OUT_BF16) ((u16*)Cout)[(size_t)(rowb+r)*Nn_ + col] = f2bf(v);
        else          ((float*)Cout)[(size_t)(rowb+r)*Nn_ + col] = v;
      }
    }
  }
}

// ------- V transpose: qkv v-part -> Vt[bh][d][t] (bf16) -------
__global__ void k_tv(const u16* __restrict__ qkv, u16* __restrict__ vt){
  __shared__ __align__(16) u16 sh[64][80];
  int tid = threadIdx.x;
  int tt = blockIdx.x * 64, bh = blockIdx.y;
  int b = bh >> 4, h = bh & 15;
  const u16* src = qkv + (size_t)(b*Tn + tt)*N1n + 2*Cn + h*HSn;
  int r = tid >> 3, c8 = (tid & 7) * 8;
  #pragma unroll
  for (int p=0;p<2;p++){
    int rr2 = r + 32*p;
    *(uint4*)&sh[rr2][c8] = *(const uint4*)&src[(size_t)rr2*N1n + c8];
  }
  __syncthreads();
  u16* dst = vt + (size_t)bh*HSn*Tn + tt;
  #pragma unroll
  for (int p=0;p<2;p++){
    int d = r + 32*p;
    u32 w0 = (u32)sh[c8+0][d] | ((u32)sh[c8+1][d] << 16);
    u32 w1 = (u32)sh[c8+2][d] | ((u32)sh[c8+3][d] << 16);
    u32 w2 = (u32)sh[c8+4][d] | ((u32)sh[c8+5][d] << 16);
    u32 w3 = (u32)sh[c8+6][d] | ((u32)sh[c8+7][d] << 16);
    uint4 pk; pk.x=w0; pk.y=w1; pk.z=w2; pk.w=w3;
    *(uint4*)&dst[(size_t)d*Tn + c8] = pk;
  }
}

// ---------------- causal flash attention, 32x32 swapped-QK^T ----------------
// 1D grid of 512 blocks: blk -> (xcd, bh, pr); each block runs q-tiles pr and
// 15-pr sequentially (uniform 34 KV-tiles/block). All 8 blocks of a head on
// one XCD (K+V of 8 heads = 4MB = one XCD L2).
// Q pre-scaled by 0.125*log2e -> logits in exp2 domain (no per-elem scale mul).
__global__ __launch_bounds__(256, 2)
void k_attn(const u16* __restrict__ qkv, const u16* __restrict__ vt, u16* __restrict__ yb){
  __shared__ __align__(16) u16 Ks[2][64*64];
  __shared__ __align__(16) u16 Vs[2][64*64];
  int tid = threadIdx.x, wave = tid >> 6, lane = tid & 63;
  int ql = lane & 31, hi = lane >> 5;
  int blk = blockIdx.x;
  int xcd = blk & 7, sub = blk >> 3;
  int bh  = xcd + 8*(sub & 7);
  int pr  = sub >> 3;                  // 0..7
  int b = bh >> 4, h = bh & 15;

  const u16* Kbase = qkv + (size_t)b*Tn*N1n + Cn + h*HSn;
  const u16* Vbase = vt  + (size_t)bh*HSn*Tn;

  auto STAGE = [&](int bufi, int kt){
    int kb_ = kt*64;
    #pragma unroll
    for (int it=0; it<2; ++it){
      int off = it*4096 + tid*16;
      int row = off >> 7;
      int cb  = off & 127;
      int gc  = (cb ^ ((row & 7) << 4)) >> 1;   // pre-swizzled source column
      gload_lds16(Kbase + (size_t)(kb_ + row)*N1n + gc,
                  (char*)&Ks[bufi][0] + it*4096 + (wave << 10));
      gload_lds16(Vbase + (size_t)row*Tn + kb_ + gc,
                  (char*)&Vs[bufi][0] + it*4096 + (wave << 10));
    }
  };

  const float QSC = 0.125f * 1.44269504f;   // fold 1/sqrt(64) and log2(e) into Q

  #pragma unroll 1
  for (int ps=0; ps<2; ++ps){
    int qt = ps ? (15 - pr) : pr;
    int q0 = qt * 128;
    int qw0 = q0 + wave*32;
    int qg  = qw0 + ql;
    int ntiles = 2*qt + 2;

    // Q B-frags (col=q=lane&31, k=d = dc*16 + hi*8 + j), pre-scaled
    const u16* Qp = qkv + (size_t)(b*Tn + qg)*N1n + h*HSn;
    short8 qf[4];
    #pragma unroll
    for (int dc=0; dc<4; ++dc){
      union { short8 v; u32 w[4]; } qa;
      qa.v = *(const short8*)&Qp[dc*16 + hi*8];
      #pragma unroll
      for (int t=0; t<4; ++t){
        u32 w = qa.w[t];
        float lo = __uint_as_float(w << 16);
        float hf = __uint_as_float(w & 0xffff0000u);
        qa.w[t] = pkbf(lo*QSC, hf*QSC);
      }
      qf[dc] = qa.v;
    }

    f32x16 accO[2];
    #pragma unroll
    for (int f=0; f<2; ++f)
      #pragma unroll
      for (int r=0; r<16; ++r) accO[f][r] = 0.f;
    float m_ = -1e30f, l_ = 0.f;

    STAGE(0, 0);
    asm volatile("s_waitcnt vmcnt(0)" ::: "memory");
    __syncthreads();
    int buf = 0;

    for (int kt=0; kt<ntiles; ++kt){
      if (kt+1 < ntiles) STAGE(buf^1, kt+1);
      const char* Ksb = (const char*)&Ks[buf][0];
      const char* Vsb = (const char*)&Vs[buf][0];
      #pragma unroll
      for (int ksub=0; ksub<2; ++ksub){
        int kbase = kt*64 + ksub*32;
        if (kbase <= qw0 + 31){
          // ---- QK^T (swapped): S^T[k][q], already log2-domain ----
          f32x16 s;
          #pragma unroll
          for (int r=0; r<16; ++r) s[r] = 0.f;
          __builtin_amdgcn_s_setprio(1);
          #pragma unroll
          for (int dc=0; dc<4; ++dc){
            short8 kf = *(const short8*)(Ksb + ((ksub*32 + ql) << 7)
                            + ((dc*32 + hi*16) ^ ((ql & 7) << 4)));
            s = __builtin_amdgcn_mfma_f32_32x32x16_bf16(kf, qf[dc], s, 0, 0, 0);
          }
          __builtin_amdgcn_s_setprio(0);
          float p[16];
          if (kbase + 31 > qw0){
            // diagonal ksub: causal mask (k row = (r&3)+8*(r>>2)+4*hi)
            #pragma unroll
            for (int r=0; r<16; ++r){
              int krow = kbase + (r&3) + 8*(r>>2) + 4*hi;
              p[r] = (krow > qg) ? -1e30f : s[r];
            }
          } else {
            #pragma unroll
            for (int r=0; r<16; ++r) p[r] = s[r];
          }
          // ---- row max: in-lane tree + pair exchange ----
          float t0 = fmaxf(fmaxf(fmaxf(p[0],p[1]),fmaxf(p[2],p[3])),
                           fmaxf(fmaxf(p[4],p[5]),fmaxf(p[6],p[7])));
          float t1 = fmaxf(fmaxf(fmaxf(p[8],p[9]),fmaxf(p[10],p[11])),
                           fmaxf(fmaxf(p[12],p[13]),fmaxf(p[14],p[15])));
          float tm = fmaxf(t0, t1);
          tm = fmaxf(tm, __shfl_xor(tm, 32));
          // ---- defer-max rescale (THR=8 in log2 units) ----
          if (!__all(tm - m_ <= 8.0f)){
            float mn = fmaxf(m_, tm);
            float al = fexp2(m_ - mn);
            m_ = mn; l_ *= al;
            #pragma unroll
            for (int f=0; f<2; ++f)
              #pragma unroll
              for (int r=0; r<16; ++r) accO[f][r] *= al;
          }
          float ls = 0.f;
          #pragma unroll
          for (int r=0; r<16; ++r){ float e = fexp2(p[r] - m_); p[r] = e; ls += e; }
          l_ += ls + __shfl_xor(ls, 32);
          // ---- P -> bf16 B-frags (2 K-slices of 16) + PV ----
          #pragma unroll
          for (int ks=0; ks<2; ++ks){
            int pb = ks*8;
            u32 a0  = pkbf(p[pb+0], p[pb+1]);
            u32 a1  = pkbf(p[pb+2], p[pb+3]);
            u32 b0w = pkbf(p[pb+4], p[pb+5]);
            u32 b1w = pkbf(p[pb+6], p[pb+7]);
            u32 a0x = (u32)__shfl_xor((int)a0, 32);
            u32 a1x = (u32)__shfl_xor((int)a1, 32);
            u32 b0x = (u32)__shfl_xor((int)b0w, 32);
            u32 b1x = (u32)__shfl_xor((int)b1w, 32);
            union { u32 w[4]; short8 v; } pu;
            pu.w[0] = hi ? b0x : a0;
            pu.w[1] = hi ? b1x : a1;
            pu.w[2] = hi ? b0w : a0x;
            pu.w[3] = hi ? b1w : a1x;
            __builtin_amdgcn_s_setprio(1);
            #pragma unroll
            for (int f=0; f<2; ++f){
              short8 vf = *(const short8*)(Vsb + ((f*32 + ql) << 7)
                              + ((ksub*64 + ks*32 + hi*16) ^ ((ql & 7) << 4)));
              accO[f] = __builtin_amdgcn_mfma_f32_32x32x16_bf16(vf, pu.v, accO[f], 0, 0, 0);
            }
            __builtin_amdgcn_s_setprio(0);
          }
        }
      }
      asm volatile("s_waitcnt vmcnt(0)" ::: "memory");
      __syncthreads();
      buf ^= 1;
    }

    // ---- epilogue: O^T[d][q] -> yb[q][d], normalize by l ----
    float rl = 1.0f / l_;
    u16* yp = yb + (size_t)(b*Tn + qg)*Cn + h*HSn;
    #pragma unroll
    for (int f=0; f<2; ++f)
      #pragma unroll
      for (int rq=0; rq<4; ++rq){
        int d0 = f*32 + rq*8 + hi*4;
        float v0 = accO[f][rq*4+0]*rl, v1 = accO[f][rq*4+1]*rl;
        float v2 = accO[f][rq*4+2]*rl, v3 = accO[f][rq*4+3]*rl;
        uint2 pk2;
        pk2.x = (u32)f2bf(v0) | ((u32)f2bf(v1) << 16);
        pk2.y = (u32)f2bf(v2) | ((u32)f2bf(v3) << 16);
        *(uint2*)&yp[d0] = pk2;
      }
  }
}

extern "C" void kernel_launch(void* const* d_in, const int* in_sizes, int n_in,
                              void* d_out, int out_size, void* d_ws, size_t ws_size,
                              hipStream_t stream)
{
  const float* x      = (const float*)d_in[0];
  const float* w_attn = (const float*)d_in[1];
  const float* b_attn = (const float*)d_in[2];
  const float* w_proj = (const float*)d_in[3];
  const float* b_proj = (const float*)d_in[4];
  float* out = (float*)d_out;
  char* ws = (char*)d_ws;

  size_t off = 0;
  u16* xb  = (u16*)(ws + off); off += (size_t)Mn*Cn*2;
  u16* waT = (u16*)(ws + off); off += (size_t)N1n*Cn*2;
  u16* wpT = (u16*)(ws + off); off += (size_t)Cn*Cn*2;
  u16* qkv = (u16*)(ws + off); off += (size_t)Mn*N1n*2;
  u16* vt  = (u16*)(ws + off); off += (size_t)Bn*Hn*HSn*Tn*2;
  u16* yb  = (u16*)(ws + off); off += (size_t)Mn*Cn*2;

  k_cvt<<<dim3(Mn*Cn/8/256), 256, 0, stream>>>(x, xb, Mn*Cn/8);
  k_tcvt<<<dim3(N1n/64, Cn/64), 256, 0, stream>>>(w_attn, waT, Cn, N1n);
  k_tcvt<<<dim3(Cn/64, Cn/64), 256, 0, stream>>>(w_proj, wpT, Cn, Cn);
  k_gemm<1><<<dim3(N1n/128, Mn/128), 256, 0, stream>>>(xb, waT, b_attn, qkv, N1n, Cn);
  k_tv<<<dim3(Tn/64, Bn*Hn), 256, 0, stream>>>(qkv, vt);
  k_attn<<<dim3(512), 256, 0, stream>>>(qkv, vt, yb);
  k_gemm<0><<<dim3(Cn/128, Mn/128), 256, 0, stream>>>(yb, wpT, b_proj, out, Cn, Cn);
}

// Round 4
// 178.323 us; speedup vs baseline: 3.1832x; 1.0561x over previous
//
#include <hip/hip_runtime.h>
#include <stdint.h>

#define Bn 4
#define Tn 2048
#define Cn 1024
#define Hn 16
#define HSn 64
#define Mn (Bn*Tn)
#define N1n (3*Cn)

typedef unsigned short u16;
typedef unsigned int u32;
typedef __attribute__((ext_vector_type(8))) short short8;
typedef __attribute__((ext_vector_type(4))) float f32x4;
typedef __attribute__((ext_vector_type(16))) float f32x16;

__device__ __forceinline__ u16 f2bf(float f){
  u32 u = __float_as_uint(f);
  u += 0x7fffu + ((u >> 16) & 1u);
  return (u16)(u >> 16);
}

__device__ __forceinline__ u32 pkbf(float lo, float hi_){
  u32 r; asm("v_cvt_pk_bf16_f32 %0, %1, %2" : "=v"(r) : "v"(lo), "v"(hi_)); return r;
}

__device__ __forceinline__ float fexp2(float x){
  float r; asm("v_exp_f32 %0, %1" : "=v"(r) : "v"(x)); return r;
}

__device__ __forceinline__ void gload_lds16(const void* g, void* l){
  __builtin_amdgcn_global_load_lds(
      (const __attribute__((address_space(1))) u32*)g,
      (__attribute__((address_space(3))) u32*)l, 16, 0, 0);
}

#define BARRIER() __builtin_amdgcn_s_barrier()
#define WAITLGKM() asm volatile("s_waitcnt lgkmcnt(0)" ::: "memory")

// ---------------- flat f32 -> bf16 convert ----------------
__global__ void k_cvt(const float* __restrict__ in, u16* __restrict__ out, int n8){
  int i = blockIdx.x*256 + threadIdx.x;
  if (i >= n8) return;
  const float4* p = (const float4*)(in) + (size_t)i*2;
  float4 a = p[0], b = p[1];
  uint4 r;
  r.x = (u32)f2bf(a.x) | ((u32)f2bf(a.y) << 16);
  r.y = (u32)f2bf(a.z) | ((u32)f2bf(a.w) << 16);
  r.z = (u32)f2bf(b.x) | ((u32)f2bf(b.y) << 16);
  r.w = (u32)f2bf(b.z) | ((u32)f2bf(b.w) << 16);
  *((uint4*)(out) + i) = r;
}

// ------- transpose + convert: in f32 [R][Cc] -> out bf16 [Cc][R] -------
__global__ void k_tcvt(const float* __restrict__ in, u16* __restrict__ out, int R, int Cc){
  __shared__ float sh[64][68];
  int tid = threadIdx.x;
  int c0 = blockIdx.x*64, r0 = blockIdx.y*64;
  int rr = tid >> 4, c4 = (tid & 15) * 4;
  #pragma unroll
  for (int p=0;p<4;p++){
    int r = rr + 16*p;
    *(float4*)&sh[r][c4] = *(const float4*)&in[(size_t)(r0+r)*Cc + c0 + c4];
  }
  __syncthreads();
  #pragma unroll
  for (int p=0;p<4;p++){
    int oc = rr + 16*p;
    u32 w0 = (u32)f2bf(sh[c4+0][oc]) | ((u32)f2bf(sh[c4+1][oc]) << 16);
    u32 w1 = (u32)f2bf(sh[c4+2][oc]) | ((u32)f2bf(sh[c4+3][oc]) << 16);
    uint2 pk; pk.x = w0; pk.y = w1;
    *(uint2*)&out[(size_t)(c0+oc)*R + r0 + c4] = pk;
  }
}

// ------------- 8-phase-style GEMM: C = A . Bt^T + bias -------------
// A [M][1024] bf16, Bt [N][1024] bf16. Tile 256x128, BK=64, 8 waves (4Mx2N),
// per-wave C 64x64. 2 phases per K-tile, 16 MFMA/phase, counted vmcnt(3),
// raw s_barrier (no vmcnt drain), LDS XOR-swizzle (row&7)<<4.
template <int OUT_BF16>
__global__ __launch_bounds__(512, 1)
void k_gemm8(const u16* __restrict__ A, const u16* __restrict__ Bt,
             const float* __restrict__ bias, void* __restrict__ Cout,
             int Nn_, int nx)
{
  extern __shared__ char smem[];           // As[2][256*64]u16 (64KB) + Bs[2][128*64]u16 (32KB)
  const int nkt = 16;                      // K=1024 / 64
  int tid = threadIdx.x;
  int wave = tid >> 6, lane = tid & 63, g = lane >> 4, cl = lane & 15;
  int wm = wave >> 1, wn = wave & 1;

  int nwg = gridDim.x;                     // multiple of 8
  int cpx = nwg >> 3;
  int wg = (blockIdx.x & 7) * cpx + (blockIdx.x >> 3);
  int bx = wg % nx, by = wg / nx;
  int m0 = by * 256, n0 = bx * 128;

  // staging geometry: unit = 8KB = 64 rows x 128B; 1 load/thread/unit
  int srow = tid >> 3;
  int scolb = (tid & 7) << 4;
  int ssw = scolb ^ ((srow & 7) << 4);     // pre-swizzled source column
  const char* Agp = (const char*)A  + (size_t)(m0 + srow) * 2048 + ssw;
  const char* Bgp = (const char*)Bt + (size_t)(n0 + srow) * 2048 + ssw;
  char* AsL = smem;                        // +((t&1)<<15) + unit<<13
  char* BsL = smem + 65536;                // +((t&1)<<14) + unit<<13

  #define SA(t_,u_) gload_lds16(Agp + (size_t)(u_)*131072 + (size_t)(t_)*128, \
                                AsL + (((t_)&1)<<15) + ((u_)<<13) + (wave<<10))
  #define SB(t_,u_) gload_lds16(Bgp + (size_t)(u_)*131072 + (size_t)(t_)*128, \
                                BsL + (((t_)&1)<<14) + ((u_)<<13) + (wave<<10))

  f32x4 acc[4][4];
  #pragma unroll
  for (int i=0;i<4;i++)
    #pragma unroll
    for (int j=0;j<4;j++) acc[i][j] = (f32x4){0.f,0.f,0.f,0.f};

  // prologue: flat stage stream [A012(0)][A3 B0 B1(0)][A012(1)]
  SA(0,0); SA(0,1); SA(0,2);
  SA(0,3); SB(0,0); SB(0,1);
  SA(1,0); SA(1,1); SA(1,2);
  asm volatile("s_waitcnt vmcnt(3)" ::: "memory");   // tile 0 fully landed
  BARRIER();

  for (int t=0; t<nkt; ++t){
    const char* Asb = smem + ((t&1)<<15);
    const char* Bsb = smem + 65536 + ((t&1)<<14);
    short8 a[4][2], bq[2][2];
    // ---- phase 1: read all A frags + B[nh=0]; stage A3,B0,B1 of t+1 ----
    #pragma unroll
    for (int i=0;i<4;i++){
      int row = wm*64 + i*16 + cl;
      #pragma unroll
      for (int ks=0;ks<2;ks++)
        a[i][ks] = *(const short8*)(Asb + row*128 + ((ks*64 + g*16) ^ ((row&7)<<4)));
    }
    #pragma unroll
    for (int j=0;j<2;j++){
      int row = wn*64 + j*16 + cl;
      #pragma unroll
      for (int ks=0;ks<2;ks++)
        bq[j][ks] = *(const short8*)(Bsb + row*128 + ((ks*64 + g*16) ^ ((row&7)<<4)));
    }
    if (t+1 < nkt){ SA(t+1,3); SB(t+1,0); SB(t+1,1); }
    BARRIER(); WAITLGKM();
    __builtin_amdgcn_s_setprio(1);
    #pragma unroll
    for (int ks=0;ks<2;ks++)
      #pragma unroll
      for (int i=0;i<4;i++)
        #pragma unroll
        for (int j=0;j<2;j++)
          acc[i][j] = __builtin_amdgcn_mfma_f32_16x16x32_bf16(a[i][ks], bq[j][ks], acc[i][j], 0, 0, 0);
    __builtin_amdgcn_s_setprio(0);
    BARRIER();
    // ---- phase 2: read B[nh=1]; stage A0,A1,A2 of t+2; counted vmcnt ----
    #pragma unroll
    for (int j=0;j<2;j++){
      int row = wn*64 + 32 + j*16 + cl;
      #pragma unroll
      for (int ks=0;ks<2;ks++)
        bq[j][ks] = *(const short8*)(Bsb + row*128 + ((ks*64 + g*16) ^ ((row&7)<<4)));
    }
    if (t+2 < nkt){
      SA(t+2,0); SA(t+2,1); SA(t+2,2);
      asm volatile("s_waitcnt vmcnt(3)" ::: "memory"); // all but last 3 units landed -> tile t+1 ready
    } else {
      asm volatile("s_waitcnt vmcnt(0)" ::: "memory");
    }
    BARRIER(); WAITLGKM();
    __builtin_amdgcn_s_setprio(1);
    #pragma unroll
    for (int ks=0;ks<2;ks++)
      #pragma unroll
      for (int i=0;i<4;i++)
        #pragma unroll
        for (int j=0;j<2;j++)
          acc[i][2+j] = __builtin_amdgcn_mfma_f32_16x16x32_bf16(a[i][ks], bq[j][ks], acc[i][2+j], 0, 0, 0);
    __builtin_amdgcn_s_setprio(0);
    BARRIER();
  }
  #undef SA
  #undef SB

  // epilogue: D frag layout col=lane&15, row=4*(lane>>4)+reg
  #pragma unroll
  for (int jj=0;jj<4;jj++){
    int col = n0 + wn*64 + jj*16 + cl;
    float bj = bias[col];
    #pragma unroll
    for (int i=0;i<4;i++){
      int rowb = m0 + wm*64 + i*16 + g*4;
      #pragma unroll
      for (int r=0;r<4;r++){
        float v = acc[i][jj][r] + bj;
        if (OUT_BF16) ((u16*)Cout)[(size_t)(rowb+r)*Nn_ + col] = f2bf(v);
        else          ((float*)Cout)[(size_t)(rowb+r)*Nn_ + col] = v;
      }
    }
  }
}

// ------- V transpose: qkv v-part -> Vt[bh][d][t] (bf16) -------
__global__ void k_tv(const u16* __restrict__ qkv, u16* __restrict__ vt){
  __shared__ __align__(16) u16 sh[64][80];
  int tid = threadIdx.x;
  int tt = blockIdx.x * 64, bh = blockIdx.y;
  int b = bh >> 4, h = bh & 15;
  const u16* src = qkv + (size_t)(b*Tn + tt)*N1n + 2*Cn + h*HSn;
  int r = tid >> 3, c8 = (tid & 7) * 8;
  #pragma unroll
  for (int p=0;p<2;p++){
    int rr2 = r + 32*p;
    *(uint4*)&sh[rr2][c8] = *(const uint4*)&src[(size_t)rr2*N1n + c8];
  }
  __syncthreads();
  u16* dst = vt + (size_t)bh*HSn*Tn + tt;
  #pragma unroll
  for (int p=0;p<2;p++){
    int d = r + 32*p;
    u32 w0 = (u32)sh[c8+0][d] | ((u32)sh[c8+1][d] << 16);
    u32 w1 = (u32)sh[c8+2][d] | ((u32)sh[c8+3][d] << 16);
    u32 w2 = (u32)sh[c8+4][d] | ((u32)sh[c8+5][d] << 16);
    u32 w3 = (u32)sh[c8+6][d] | ((u32)sh[c8+7][d] << 16);
    uint4 pk; pk.x=w0; pk.y=w1; pk.z=w2; pk.w=w3;
    *(uint4*)&dst[(size_t)d*Tn + c8] = pk;
  }
}

// ---------------- causal flash attention, 32x32 swapped-QK^T ----------------
__global__ __launch_bounds__(256, 2)
void k_attn(const u16* __restrict__ qkv, const u16* __restrict__ vt, u16* __restrict__ yb){
  __shared__ __align__(16) u16 Ks[2][64*64];
  __shared__ __align__(16) u16 Vs[2][64*64];
  int tid = threadIdx.x, wave = tid >> 6, lane = tid & 63;
  int ql = lane & 31, hi = lane >> 5;
  int blk = blockIdx.x;
  int xcd = blk & 7, sub = blk >> 3;
  int bh  = xcd + 8*(sub & 7);
  int pr  = sub >> 3;                  // 0..7
  int b = bh >> 4, h = bh & 15;

  const u16* Kbase = qkv + (size_t)b*Tn*N1n + Cn + h*HSn;
  const u16* Vbase = vt  + (size_t)bh*HSn*Tn;

  auto STAGE = [&](int bufi, int kt){
    int kb_ = kt*64;
    #pragma unroll
    for (int it=0; it<2; ++it){
      int off = it*4096 + tid*16;
      int row = off >> 7;
      int cb  = off & 127;
      int gc  = (cb ^ ((row & 7) << 4)) >> 1;
      gload_lds16(Kbase + (size_t)(kb_ + row)*N1n + gc,
                  (char*)&Ks[bufi][0] + it*4096 + (wave << 10));
      gload_lds16(Vbase + (size_t)row*Tn + kb_ + gc,
                  (char*)&Vs[bufi][0] + it*4096 + (wave << 10));
    }
  };

  const float QSC = 0.125f * 1.44269504f;

  #pragma unroll 1
  for (int ps=0; ps<2; ++ps){
    int qt = ps ? (15 - pr) : pr;
    int q0 = qt * 128;
    int qw0 = q0 + wave*32;
    int qg  = qw0 + ql;
    int ntiles = 2*qt + 2;

    const u16* Qp = qkv + (size_t)(b*Tn + qg)*N1n + h*HSn;
    short8 qf[4];
    #pragma unroll
    for (int dc=0; dc<4; ++dc){
      union { short8 v; u32 w[4]; } qa;
      qa.v = *(const short8*)&Qp[dc*16 + hi*8];
      #pragma unroll
      for (int t=0; t<4; ++t){
        u32 w = qa.w[t];
        float lo = __uint_as_float(w << 16);
        float hf = __uint_as_float(w & 0xffff0000u);
        qa.w[t] = pkbf(lo*QSC, hf*QSC);
      }
      qf[dc] = qa.v;
    }

    f32x16 accO[2];
    #pragma unroll
    for (int f=0; f<2; ++f)
      #pragma unroll
      for (int r=0; r<16; ++r) accO[f][r] = 0.f;
    float m_ = -1e30f, l_ = 0.f;

    STAGE(0, 0);
    asm volatile("s_waitcnt vmcnt(0)" ::: "memory");
    __syncthreads();
    int buf = 0;

    for (int kt=0; kt<ntiles; ++kt){
      if (kt+1 < ntiles) STAGE(buf^1, kt+1);
      const char* Ksb = (const char*)&Ks[buf][0];
      const char* Vsb = (const char*)&Vs[buf][0];
      #pragma unroll
      for (int ksub=0; ksub<2; ++ksub){
        int kbase = kt*64 + ksub*32;
        if (kbase <= qw0 + 31){
          f32x16 s;
          #pragma unroll
          for (int r=0; r<16; ++r) s[r] = 0.f;
          __builtin_amdgcn_s_setprio(1);
          #pragma unroll
          for (int dc=0; dc<4; ++dc){
            short8 kf = *(const short8*)(Ksb + ((ksub*32 + ql) << 7)
                            + ((dc*32 + hi*16) ^ ((ql & 7) << 4)));
            s = __builtin_amdgcn_mfma_f32_32x32x16_bf16(kf, qf[dc], s, 0, 0, 0);
          }
          __builtin_amdgcn_s_setprio(0);
          float p[16];
          if (kbase + 31 > qw0){
            #pragma unroll
            for (int r=0; r<16; ++r){
              int krow = kbase + (r&3) + 8*(r>>2) + 4*hi;
              p[r] = (krow > qg) ? -1e30f : s[r];
            }
          } else {
            #pragma unroll
            for (int r=0; r<16; ++r) p[r] = s[r];
          }
          float t0 = fmaxf(fmaxf(fmaxf(p[0],p[1]),fmaxf(p[2],p[3])),
                           fmaxf(fmaxf(p[4],p[5]),fmaxf(p[6],p[7])));
          float t1 = fmaxf(fmaxf(fmaxf(p[8],p[9]),fmaxf(p[10],p[11])),
                           fmaxf(fmaxf(p[12],p[13]),fmaxf(p[14],p[15])));
          float tm = fmaxf(t0, t1);
          tm = fmaxf(tm, __shfl_xor(tm, 32));
          if (!__all(tm - m_ <= 8.0f)){
            float mn = fmaxf(m_, tm);
            float al = fexp2(m_ - mn);
            m_ = mn; l_ *= al;
            #pragma unroll
            for (int f=0; f<2; ++f)
              #pragma unroll
              for (int r=0; r<16; ++r) accO[f][r] *= al;
          }
          float ls = 0.f;
          #pragma unroll
          for (int r=0; r<16; ++r){ float e = fexp2(p[r] - m_); p[r] = e; ls += e; }
          l_ += ls + __shfl_xor(ls, 32);
          #pragma unroll
          for (int ks=0; ks<2; ++ks){
            int pb = ks*8;
            u32 a0  = pkbf(p[pb+0], p[pb+1]);
            u32 a1  = pkbf(p[pb+2], p[pb+3]);
            u32 b0w = pkbf(p[pb+4], p[pb+5]);
            u32 b1w = pkbf(p[pb+6], p[pb+7]);
            u32 a0x = (u32)__shfl_xor((int)a0, 32);
            u32 a1x = (u32)__shfl_xor((int)a1, 32);
            u32 b0x = (u32)__shfl_xor((int)b0w, 32);
            u32 b1x = (u32)__shfl_xor((int)b1w, 32);
            union { u32 w[4]; short8 v; } pu;
            pu.w[0] = hi ? b0x : a0;
            pu.w[1] = hi ? b1x : a1;
            pu.w[2] = hi ? b0w : a0x;
            pu.w[3] = hi ? b1w : a1x;
            __builtin_amdgcn_s_setprio(1);
            #pragma unroll
            for (int f=0; f<2; ++f){
              short8 vf = *(const short8*)(Vsb + ((f*32 + ql) << 7)
                              + ((ksub*64 + ks*32 + hi*16) ^ ((ql & 7) << 4)));
              accO[f] = __builtin_amdgcn_mfma_f32_32x32x16_bf16(vf, pu.v, accO[f], 0, 0, 0);
            }
            __builtin_amdgcn_s_setprio(0);
          }
        }
      }
      asm volatile("s_waitcnt vmcnt(0)" ::: "memory");
      __syncthreads();
      buf ^= 1;
    }

    float rl = 1.0f / l_;
    u16* yp = yb + (size_t)(b*Tn + qg)*Cn + h*HSn;
    #pragma unroll
    for (int f=0; f<2; ++f)
      #pragma unroll
      for (int rq=0; rq<4; ++rq){
        int d0 = f*32 + rq*8 + hi*4;
        float v0 = accO[f][rq*4+0]*rl, v1 = accO[f][rq*4+1]*rl;
        float v2 = accO[f][rq*4+2]*rl, v3 = accO[f][rq*4+3]*rl;
        uint2 pk2;
        pk2.x = (u32)f2bf(v0) | ((u32)f2bf(v1) << 16);
        pk2.y = (u32)f2bf(v2) | ((u32)f2bf(v3) << 16);
        *(uint2*)&yp[d0] = pk2;
      }
  }
}

extern "C" void kernel_launch(void* const* d_in, const int* in_sizes, int n_in,
                              void* d_out, int out_size, void* d_ws, size_t ws_size,
                              hipStream_t stream)
{
  const float* x      = (const float*)d_in[0];
  const float* w_attn = (const float*)d_in[1];
  const float* b_attn = (const float*)d_in[2];
  const float* w_proj = (const float*)d_in[3];
  const float* b_proj = (const float*)d_in[4];
  float* out = (float*)d_out;
  char* ws = (char*)d_ws;

  size_t off = 0;
  u16* xb  = (u16*)(ws + off); off += (size_t)Mn*Cn*2;
  u16* waT = (u16*)(ws + off); off += (size_t)N1n*Cn*2;
  u16* wpT = (u16*)(ws + off); off += (size_t)Cn*Cn*2;
  u16* qkv = (u16*)(ws + off); off += (size_t)Mn*N1n*2;
  u16* vt  = (u16*)(ws + off); off += (size_t)Bn*Hn*HSn*Tn*2;
  u16* yb  = (u16*)(ws + off); off += (size_t)Mn*Cn*2;

  // allow 96KB dynamic LDS for the 8-phase GEMM (no-op if already allowed)
  (void)hipFuncSetAttribute((const void*)k_gemm8<1>,
        hipFuncAttributeMaxDynamicSharedMemorySize, 98304);
  (void)hipFuncSetAttribute((const void*)k_gemm8<0>,
        hipFuncAttributeMaxDynamicSharedMemorySize, 98304);

  k_cvt<<<dim3(Mn*Cn/8/256), 256, 0, stream>>>(x, xb, Mn*Cn/8);
  k_tcvt<<<dim3(N1n/64, Cn/64), 256, 0, stream>>>(w_attn, waT, Cn, N1n);
  k_tcvt<<<dim3(Cn/64, Cn/64), 256, 0, stream>>>(w_proj, wpT, Cn, Cn);
  k_gemm8<1><<<dim3((Mn/256)*(N1n/128)), 512, 98304, stream>>>(xb, waT, b_attn, qkv, N1n, N1n/128);
  k_tv<<<dim3(Tn/64, Bn*Hn), 256, 0, stream>>>(qkv, vt);
  k_attn<<<dim3(512), 256, 0, stream>>>(qkv, vt, yb);
  k_gemm8<0><<<dim3((Mn/256)*(Cn/128)), 512, 98304, stream>>>(yb, wpT, b_proj, out, Cn, Cn/128);
}

// Round 5
// 163.650 us; speedup vs baseline: 3.4687x; 1.0897x over previous
//
#include <hip/hip_runtime.h>
#include <stdint.h>

#define Bn 4
#define Tn 2048
#define Cn 1024
#define Hn 16
#define HSn 64
#define Mn (Bn*Tn)
#define N1n (3*Cn)

typedef unsigned short u16;
typedef unsigned int u32;
typedef __attribute__((ext_vector_type(8))) short short8;
typedef __attribute__((ext_vector_type(4))) float f32x4;
typedef __attribute__((ext_vector_type(16))) float f32x16;

__device__ __forceinline__ u16 f2bf(float f){
  u32 u = __float_as_uint(f);
  u += 0x7fffu + ((u >> 16) & 1u);
  return (u16)(u >> 16);
}

__device__ __forceinline__ u32 pkbf(float lo, float hi_){
  u32 r; asm("v_cvt_pk_bf16_f32 %0, %1, %2" : "=v"(r) : "v"(lo), "v"(hi_)); return r;
}

__device__ __forceinline__ float fexp2(float x){
  float r; asm("v_exp_f32 %0, %1" : "=v"(r) : "v"(x)); return r;
}

// (na,nb) = swap: lane<32: na=a[l], nb=a[l+32]; lane>=32: na=b[l-32], nb=b[l]
__device__ __forceinline__ void plswap(u32 &a, u32 &b){
  auto r = __builtin_amdgcn_permlane32_swap(a, b, false, false);
  a = r[0]; b = r[1];
}

__device__ __forceinline__ void gload_lds16(const void* g, void* l){
  __builtin_amdgcn_global_load_lds(
      (const __attribute__((address_space(1))) u32*)g,
      (__attribute__((address_space(3))) u32*)l, 16, 0, 0);
}

#define BARRIER() __builtin_amdgcn_s_barrier()
#define WAITLGKM() asm volatile("s_waitcnt lgkmcnt(0)" ::: "memory")

// ---------------- flat f32 -> bf16 convert ----------------
__global__ void k_cvt(const float* __restrict__ in, u16* __restrict__ out, int n8){
  int i = blockIdx.x*256 + threadIdx.x;
  if (i >= n8) return;
  const float4* p = (const float4*)(in) + (size_t)i*2;
  float4 a = p[0], b = p[1];
  uint4 r;
  r.x = (u32)f2bf(a.x) | ((u32)f2bf(a.y) << 16);
  r.y = (u32)f2bf(a.z) | ((u32)f2bf(a.w) << 16);
  r.z = (u32)f2bf(b.x) | ((u32)f2bf(b.y) << 16);
  r.w = (u32)f2bf(b.z) | ((u32)f2bf(b.w) << 16);
  *((uint4*)(out) + i) = r;
}

// ------- transpose + convert: in f32 [R][Cc] -> out bf16 [Cc][R] -------
__global__ void k_tcvt(const float* __restrict__ in, u16* __restrict__ out, int R, int Cc){
  __shared__ float sh[64][68];
  int tid = threadIdx.x;
  int c0 = blockIdx.x*64, r0 = blockIdx.y*64;
  int rr = tid >> 4, c4 = (tid & 15) * 4;
  #pragma unroll
  for (int p=0;p<4;p++){
    int r = rr + 16*p;
    *(float4*)&sh[r][c4] = *(const float4*)&in[(size_t)(r0+r)*Cc + c0 + c4];
  }
  __syncthreads();
  #pragma unroll
  for (int p=0;p<4;p++){
    int oc = rr + 16*p;
    u32 w0 = (u32)f2bf(sh[c4+0][oc]) | ((u32)f2bf(sh[c4+1][oc]) << 16);
    u32 w1 = (u32)f2bf(sh[c4+2][oc]) | ((u32)f2bf(sh[c4+3][oc]) << 16);
    uint2 pk; pk.x = w0; pk.y = w1;
    *(uint2*)&out[(size_t)(c0+oc)*R + r0 + c4] = pk;
  }
}

// ------------- 8-phase-style GEMM: C = A . Bt^T + bias -------------
template <int OUT_BF16>
__global__ __launch_bounds__(512, 1)
void k_gemm8(const u16* __restrict__ A, const u16* __restrict__ Bt,
             const float* __restrict__ bias, void* __restrict__ Cout,
             int Nn_, int nx)
{
  extern __shared__ char smem[];
  const int nkt = 16;
  int tid = threadIdx.x;
  int wave = tid >> 6, lane = tid & 63, g = lane >> 4, cl = lane & 15;
  int wm = wave >> 1, wn = wave & 1;

  int nwg = gridDim.x;
  int cpx = nwg >> 3;
  int wg = (blockIdx.x & 7) * cpx + (blockIdx.x >> 3);
  int bx = wg % nx, by = wg / nx;
  int m0 = by * 256, n0 = bx * 128;

  int srow = tid >> 3;
  int scolb = (tid & 7) << 4;
  int ssw = scolb ^ ((srow & 7) << 4);
  const char* Agp = (const char*)A  + (size_t)(m0 + srow) * 2048 + ssw;
  const char* Bgp = (const char*)Bt + (size_t)(n0 + srow) * 2048 + ssw;
  char* AsL = smem;
  char* BsL = smem + 65536;

  #define SA(t_,u_) gload_lds16(Agp + (size_t)(u_)*131072 + (size_t)(t_)*128, \
                                AsL + (((t_)&1)<<15) + ((u_)<<13) + (wave<<10))
  #define SB(t_,u_) gload_lds16(Bgp + (size_t)(u_)*131072 + (size_t)(t_)*128, \
                                BsL + (((t_)&1)<<14) + ((u_)<<13) + (wave<<10))

  f32x4 acc[4][4];
  #pragma unroll
  for (int i=0;i<4;i++)
    #pragma unroll
    for (int j=0;j<4;j++) acc[i][j] = (f32x4){0.f,0.f,0.f,0.f};

  SA(0,0); SA(0,1); SA(0,2);
  SA(0,3); SB(0,0); SB(0,1);
  SA(1,0); SA(1,1); SA(1,2);
  asm volatile("s_waitcnt vmcnt(3)" ::: "memory");
  BARRIER();

  for (int t=0; t<nkt; ++t){
    const char* Asb = smem + ((t&1)<<15);
    const char* Bsb = smem + 65536 + ((t&1)<<14);
    short8 a[4][2], bq[2][2];
    #pragma unroll
    for (int i=0;i<4;i++){
      int row = wm*64 + i*16 + cl;
      #pragma unroll
      for (int ks=0;ks<2;ks++)
        a[i][ks] = *(const short8*)(Asb + row*128 + ((ks*64 + g*16) ^ ((row&7)<<4)));
    }
    #pragma unroll
    for (int j=0;j<2;j++){
      int row = wn*64 + j*16 + cl;
      #pragma unroll
      for (int ks=0;ks<2;ks++)
        bq[j][ks] = *(const short8*)(Bsb + row*128 + ((ks*64 + g*16) ^ ((row&7)<<4)));
    }
    if (t+1 < nkt){ SA(t+1,3); SB(t+1,0); SB(t+1,1); }
    BARRIER(); WAITLGKM();
    __builtin_amdgcn_s_setprio(1);
    #pragma unroll
    for (int ks=0;ks<2;ks++)
      #pragma unroll
      for (int i=0;i<4;i++)
        #pragma unroll
        for (int j=0;j<2;j++)
          acc[i][j] = __builtin_amdgcn_mfma_f32_16x16x32_bf16(a[i][ks], bq[j][ks], acc[i][j], 0, 0, 0);
    __builtin_amdgcn_s_setprio(0);
    BARRIER();
    #pragma unroll
    for (int j=0;j<2;j++){
      int row = wn*64 + 32 + j*16 + cl;
      #pragma unroll
      for (int ks=0;ks<2;ks++)
        bq[j][ks] = *(const short8*)(Bsb + row*128 + ((ks*64 + g*16) ^ ((row&7)<<4)));
    }
    if (t+2 < nkt){
      SA(t+2,0); SA(t+2,1); SA(t+2,2);
      asm volatile("s_waitcnt vmcnt(3)" ::: "memory");
    } else {
      asm volatile("s_waitcnt vmcnt(0)" ::: "memory");
    }
    BARRIER(); WAITLGKM();
    __builtin_amdgcn_s_setprio(1);
    #pragma unroll
    for (int ks=0;ks<2;ks++)
      #pragma unroll
      for (int i=0;i<4;i++)
        #pragma unroll
        for (int j=0;j<2;j++)
          acc[i][2+j] = __builtin_amdgcn_mfma_f32_16x16x32_bf16(a[i][ks], bq[j][ks], acc[i][2+j], 0, 0, 0);
    __builtin_amdgcn_s_setprio(0);
    BARRIER();
  }
  #undef SA
  #undef SB

  #pragma unroll
  for (int jj=0;jj<4;jj++){
    int col = n0 + wn*64 + jj*16 + cl;
    float bj = bias[col];
    #pragma unroll
    for (int i=0;i<4;i++){
      int rowb = m0 + wm*64 + i*16 + g*4;
      #pragma unroll
      for (int r=0;r<4;r++){
        float v = acc[i][jj][r] + bj;
        if (OUT_BF16) ((u16*)Cout)[(size_t)(rowb+r)*Nn_ + col] = f2bf(v);
        else          ((float*)Cout)[(size_t)(rowb+r)*Nn_ + col] = v;
      }
    }
  }
}

// ------- V transpose: qkv v-part -> Vt[bh][d][t] (bf16) -------
__global__ void k_tv(const u16* __restrict__ qkv, u16* __restrict__ vt){
  __shared__ __align__(16) u16 sh[64][80];
  int tid = threadIdx.x;
  int tt = blockIdx.x * 64, bh = blockIdx.y;
  int b = bh >> 4, h = bh & 15;
  const u16* src = qkv + (size_t)(b*Tn + tt)*N1n + 2*Cn + h*HSn;
  int r = tid >> 3, c8 = (tid & 7) * 8;
  #pragma unroll
  for (int p=0;p<2;p++){
    int rr2 = r + 32*p;
    *(uint4*)&sh[rr2][c8] = *(const uint4*)&src[(size_t)rr2*N1n + c8];
  }
  __syncthreads();
  u16* dst = vt + (size_t)bh*HSn*Tn + tt;
  #pragma unroll
  for (int p=0;p<2;p++){
    int d = r + 32*p;
    u32 w0 = (u32)sh[c8+0][d] | ((u32)sh[c8+1][d] << 16);
    u32 w1 = (u32)sh[c8+2][d] | ((u32)sh[c8+3][d] << 16);
    u32 w2 = (u32)sh[c8+4][d] | ((u32)sh[c8+5][d] << 16);
    u32 w3 = (u32)sh[c8+6][d] | ((u32)sh[c8+7][d] << 16);
    uint4 pk; pk.x=w0; pk.y=w1; pk.z=w2; pk.w=w3;
    *(uint4*)&dst[(size_t)d*Tn + c8] = pk;
  }
}

// ---------------- causal flash attention, 32x32 swapped-QK^T ----------------
// grid 1024: blk -> (xcd, bh, qt) with qt DESCENDING (heavy-first) so all
// blocks co-resident at t=0; 4 blocks/CU. One 128-row q-tile per block.
__global__ __launch_bounds__(256, 4)
void k_attn(const u16* __restrict__ qkv, const u16* __restrict__ vt, u16* __restrict__ yb){
  __shared__ __align__(16) u16 Ks[2][64*64];
  __shared__ __align__(16) u16 Vs[2][64*64];
  int tid = threadIdx.x, wave = tid >> 6, lane = tid & 63;
  int ql = lane & 31, hi = lane >> 5;
  int blk = blockIdx.x;
  int xcd = blk & 7, rest = blk >> 3;
  int bh  = xcd + 8*(rest & 7);
  int qt  = 15 - (rest >> 3);          // heavy q-tiles dispatch first
  int b = bh >> 4, h = bh & 15;

  const u16* Kbase = qkv + (size_t)b*Tn*N1n + Cn + h*HSn;
  const u16* Vbase = vt  + (size_t)bh*HSn*Tn;

  auto STAGE = [&](int bufi, int kt){
    int kb_ = kt*64;
    #pragma unroll
    for (int it=0; it<2; ++it){
      int off = it*4096 + tid*16;
      int row = off >> 7;
      int cb  = off & 127;
      int gc  = (cb ^ ((row & 7) << 4)) >> 1;
      gload_lds16(Kbase + (size_t)(kb_ + row)*N1n + gc,
                  (char*)&Ks[bufi][0] + it*4096 + (wave << 10));
      gload_lds16(Vbase + (size_t)row*Tn + kb_ + gc,
                  (char*)&Vs[bufi][0] + it*4096 + (wave << 10));
    }
  };

  const float QSC = 0.125f * 1.44269504f;

  int q0 = qt * 128;
  int qw0 = q0 + wave*32;
  int qg  = qw0 + ql;
  int ntiles = 2*qt + 2;

  const u16* Qp = qkv + (size_t)(b*Tn + qg)*N1n + h*HSn;
  short8 qf[4];
  #pragma unroll
  for (int dc=0; dc<4; ++dc){
    union { short8 v; u32 w[4]; } qa;
    qa.v = *(const short8*)&Qp[dc*16 + hi*8];
    #pragma unroll
    for (int t=0; t<4; ++t){
      u32 w = qa.w[t];
      float lo = __uint_as_float(w << 16);
      float hf = __uint_as_float(w & 0xffff0000u);
      qa.w[t] = pkbf(lo*QSC, hf*QSC);
    }
    qf[dc] = qa.v;
  }

  f32x16 accO[2];
  #pragma unroll
  for (int f=0; f<2; ++f)
    #pragma unroll
    for (int r=0; r<16; ++r) accO[f][r] = 0.f;
  float m_ = -1e30f, l_ = 0.f;

  STAGE(0, 0);
  asm volatile("s_waitcnt vmcnt(0)" ::: "memory");
  __syncthreads();
  int buf = 0;

  for (int kt=0; kt<ntiles; ++kt){
    if (kt+1 < ntiles) STAGE(buf^1, kt+1);
    const char* Ksb = (const char*)&Ks[buf][0];
    const char* Vsb = (const char*)&Vs[buf][0];
    #pragma unroll
    for (int ksub=0; ksub<2; ++ksub){
      int kbase = kt*64 + ksub*32;
      if (kbase <= qw0 + 31){
        f32x16 s;
        #pragma unroll
        for (int r=0; r<16; ++r) s[r] = 0.f;
        __builtin_amdgcn_s_setprio(1);
        #pragma unroll
        for (int dc=0; dc<4; ++dc){
          short8 kf = *(const short8*)(Ksb + ((ksub*32 + ql) << 7)
                          + ((dc*32 + hi*16) ^ ((ql & 7) << 4)));
          s = __builtin_amdgcn_mfma_f32_32x32x16_bf16(kf, qf[dc], s, 0, 0, 0);
        }
        __builtin_amdgcn_s_setprio(0);
        float p[16];
        if (kbase + 31 > qw0){
          #pragma unroll
          for (int r=0; r<16; ++r){
            int krow = kbase + (r&3) + 8*(r>>2) + 4*hi;
            p[r] = (krow > qg) ? -1e30f : s[r];
          }
        } else {
          #pragma unroll
          for (int r=0; r<16; ++r) p[r] = s[r];
        }
        // ---- row max: in-lane tree + permlane cross-half ----
        float t0 = fmaxf(fmaxf(fmaxf(p[0],p[1]),fmaxf(p[2],p[3])),
                         fmaxf(fmaxf(p[4],p[5]),fmaxf(p[6],p[7])));
        float t1 = fmaxf(fmaxf(fmaxf(p[8],p[9]),fmaxf(p[10],p[11])),
                         fmaxf(fmaxf(p[12],p[13]),fmaxf(p[14],p[15])));
        float tm = fmaxf(t0, t1);
        { u32 ua = __float_as_uint(tm), ub = ua; plswap(ua, ub);
          tm = fmaxf(__uint_as_float(ua), __uint_as_float(ub)); }
        if (!__all(tm - m_ <= 8.0f)){
          float mn = fmaxf(m_, tm);
          float al = fexp2(m_ - mn);
          m_ = mn; l_ *= al;
          #pragma unroll
          for (int f=0; f<2; ++f)
            #pragma unroll
            for (int r=0; r<16; ++r) accO[f][r] *= al;
        }
        float ls = 0.f;
        #pragma unroll
        for (int r=0; r<16; ++r){ float e = fexp2(p[r] - m_); p[r] = e; ls += e; }
        { u32 ua = __float_as_uint(ls), ub = ua; plswap(ua, ub);
          l_ += __uint_as_float(ua) + __uint_as_float(ub); }
        // ---- P -> bf16 B-frags via permlane32_swap + PV ----
        #pragma unroll
        for (int ks=0; ks<2; ++ks){
          int pb = ks*8;
          u32 w0 = pkbf(p[pb+0], p[pb+1]);
          u32 w1 = pkbf(p[pb+2], p[pb+3]);
          u32 w2 = pkbf(p[pb+4], p[pb+5]);
          u32 w3 = pkbf(p[pb+6], p[pb+7]);
          plswap(w0, w2);   // -> (lo: k0..1 | hi: k8..9), (lo: k4..5 | hi: k12..13)
          plswap(w1, w3);
          union { u32 w[4]; short8 v; } pu;
          pu.w[0] = w0; pu.w[1] = w1; pu.w[2] = w2; pu.w[3] = w3;
          __builtin_amdgcn_s_setprio(1);
          #pragma unroll
          for (int f=0; f<2; ++f){
            short8 vf = *(const short8*)(Vsb + ((f*32 + ql) << 7)
                            + ((ksub*64 + ks*32 + hi*16) ^ ((ql & 7) << 4)));
            accO[f] = __builtin_amdgcn_mfma_f32_32x32x16_bf16(vf, pu.v, accO[f], 0, 0, 0);
          }
          __builtin_amdgcn_s_setprio(0);
        }
      }
    }
    asm volatile("s_waitcnt vmcnt(0)" ::: "memory");
    __syncthreads();
    buf ^= 1;
  }

  float rl = 1.0f / l_;
  u16* yp = yb + (size_t)(b*Tn + qg)*Cn + h*HSn;
  #pragma unroll
  for (int f=0; f<2; ++f)
    #pragma unroll
    for (int rq=0; rq<4; ++rq){
      int d0 = f*32 + rq*8 + hi*4;
      float v0 = accO[f][rq*4+0]*rl, v1 = accO[f][rq*4+1]*rl;
      float v2 = accO[f][rq*4+2]*rl, v3 = accO[f][rq*4+3]*rl;
      uint2 pk2;
      pk2.x = (u32)f2bf(v0) | ((u32)f2bf(v1) << 16);
      pk2.y = (u32)f2bf(v2) | ((u32)f2bf(v3) << 16);
      *(uint2*)&yp[d0] = pk2;
    }
}

extern "C" void kernel_launch(void* const* d_in, const int* in_sizes, int n_in,
                              void* d_out, int out_size, void* d_ws, size_t ws_size,
                              hipStream_t stream)
{
  const float* x      = (const float*)d_in[0];
  const float* w_attn = (const float*)d_in[1];
  const float* b_attn = (const float*)d_in[2];
  const float* w_proj = (const float*)d_in[3];
  const float* b_proj = (const float*)d_in[4];
  float* out = (float*)d_out;
  char* ws = (char*)d_ws;

  size_t off = 0;
  u16* xb  = (u16*)(ws + off); off += (size_t)Mn*Cn*2;
  u16* waT = (u16*)(ws + off); off += (size_t)N1n*Cn*2;
  u16* wpT = (u16*)(ws + off); off += (size_t)Cn*Cn*2;
  u16* qkv = (u16*)(ws + off); off += (size_t)Mn*N1n*2;
  u16* vt  = (u16*)(ws + off); off += (size_t)Bn*Hn*HSn*Tn*2;
  u16* yb  = (u16*)(ws + off); off += (size_t)Mn*Cn*2;

  (void)hipFuncSetAttribute((const void*)k_gemm8<1>,
        hipFuncAttributeMaxDynamicSharedMemorySize, 98304);
  (void)hipFuncSetAttribute((const void*)k_gemm8<0>,
        hipFuncAttributeMaxDynamicSharedMemorySize, 98304);

  k_cvt<<<dim3(Mn*Cn/8/256), 256, 0, stream>>>(x, xb, Mn*Cn/8);
  k_tcvt<<<dim3(N1n/64, Cn/64), 256, 0, stream>>>(w_attn, waT, Cn, N1n);
  k_tcvt<<<dim3(Cn/64, Cn/64), 256, 0, stream>>>(w_proj, wpT, Cn, Cn);
  k_gemm8<1><<<dim3((Mn/256)*(N1n/128)), 512, 98304, stream>>>(xb, waT, b_attn, qkv, N1n, N1n/128);
  k_tv<<<dim3(Tn/64, Bn*Hn), 256, 0, stream>>>(qkv, vt);
  k_attn<<<dim3(1024), 256, 0, stream>>>(qkv, vt, yb);
  k_gemm8<0><<<dim3((Mn/256)*(Cn/128)), 512, 98304, stream>>>(yb, wpT, b_proj, out, Cn, Cn/128);
}

// Round 6
// 156.716 us; speedup vs baseline: 3.6221x; 1.0442x over previous
//
#include <hip/hip_runtime.h>
#include <stdint.h>

#define Bn 4
#define Tn 2048
#define Cn 1024
#define Hn 16
#define HSn 64
#define Mn (Bn*Tn)
#define N1n (3*Cn)

typedef unsigned short u16;
typedef unsigned int u32;
typedef __attribute__((ext_vector_type(8))) short short8;
typedef __attribute__((ext_vector_type(4))) float f32x4;
typedef __attribute__((ext_vector_type(16))) float f32x16;

__device__ __forceinline__ u16 f2bf(float f){
  u32 u = __float_as_uint(f);
  u += 0x7fffu + ((u >> 16) & 1u);
  return (u16)(u >> 16);
}

__device__ __forceinline__ u32 pkbf(float lo, float hi_){
  u32 r; asm("v_cvt_pk_bf16_f32 %0, %1, %2" : "=v"(r) : "v"(lo), "v"(hi_)); return r;
}

__device__ __forceinline__ float fexp2(float x){
  float r; asm("v_exp_f32 %0, %1" : "=v"(r) : "v"(x)); return r;
}

__device__ __forceinline__ void plswap(u32 &a, u32 &b){
  auto r = __builtin_amdgcn_permlane32_swap(a, b, false, false);
  a = r[0]; b = r[1];
}

__device__ __forceinline__ void gload_lds16(const void* g, void* l){
  __builtin_amdgcn_global_load_lds(
      (const __attribute__((address_space(1))) u32*)g,
      (__attribute__((address_space(3))) u32*)l, 16, 0, 0);
}

#define BARRIER() __builtin_amdgcn_s_barrier()
#define CFENCE() asm volatile("" ::: "memory")

// ---------------- flat f32 -> bf16 convert ----------------
__global__ void k_cvt(const float* __restrict__ in, u16* __restrict__ out, int n8){
  int i = blockIdx.x*256 + threadIdx.x;
  if (i >= n8) return;
  const float4* p = (const float4*)(in) + (size_t)i*2;
  float4 a = p[0], b = p[1];
  uint4 r;
  r.x = (u32)f2bf(a.x) | ((u32)f2bf(a.y) << 16);
  r.y = (u32)f2bf(a.z) | ((u32)f2bf(a.w) << 16);
  r.z = (u32)f2bf(b.x) | ((u32)f2bf(b.y) << 16);
  r.w = (u32)f2bf(b.z) | ((u32)f2bf(b.w) << 16);
  *((uint4*)(out) + i) = r;
}

// ------- transpose + convert: in f32 [R][Cc] -> out bf16 [Cc][R] -------
__global__ void k_tcvt(const float* __restrict__ in, u16* __restrict__ out, int R, int Cc){
  __shared__ float sh[64][68];
  int tid = threadIdx.x;
  int c0 = blockIdx.x*64, r0 = blockIdx.y*64;
  int rr = tid >> 4, c4 = (tid & 15) * 4;
  #pragma unroll
  for (int p=0;p<4;p++){
    int r = rr + 16*p;
    *(float4*)&sh[r][c4] = *(const float4*)&in[(size_t)(r0+r)*Cc + c0 + c4];
  }
  __syncthreads();
  #pragma unroll
  for (int p=0;p<4;p++){
    int oc = rr + 16*p;
    u32 w0 = (u32)f2bf(sh[c4+0][oc]) | ((u32)f2bf(sh[c4+1][oc]) << 16);
    u32 w1 = (u32)f2bf(sh[c4+2][oc]) | ((u32)f2bf(sh[c4+3][oc]) << 16);
    uint2 pk; pk.x = w0; pk.y = w1;
    *(uint2*)&out[(size_t)(c0+oc)*R + r0 + c4] = pk;
  }
}

// ---- single-phase counted-vmcnt GEMM: C = A . Bt^T + bias ----
// A [M][1024] bf16, Bt [N][1024] bf16. Tile 256x128, BK=64, 8 waves (4Mx2N),
// per-wave C 64x64. Triple-buffered LDS (144KB): stage t+2 while computing t,
// vmcnt(6) counted (confirms t+1, full-tile lead), ONE barrier per K-tile.
// MODE1: bf16 out; V-columns (>=2C) stored transposed into vt[bh][d][t].
// MODE0: f32 out.
template <int MODE>
__global__ __launch_bounds__(512, 1)
void k_gemm1p(const u16* __restrict__ A, const u16* __restrict__ Bt,
              const float* __restrict__ bias, void* __restrict__ Cout,
              u16* __restrict__ vt, int Nn_)
{
  extern __shared__ char smem[];           // As 3x32KB @0, Bs 3x16KB @98304
  const int nkt = 16;                      // K=1024 / 64
  int tid = threadIdx.x;
  int wave = tid >> 6, lane = tid & 63, g = lane >> 4, cl = lane & 15;
  int wm = wave >> 1, wn = wave & 1;

  // 2-level XCD chunking: bits [2:0]=xcd, [4:3]=byL, [7:5]=bx-in-group, [9:8]=group
  int blk = blockIdx.x;
  int by = ((blk & 7) << 2) + ((blk >> 3) & 3);
  int bx = ((blk >> 5) & 7) + ((blk >> 8) << 3);
  int m0 = by * 256, n0 = bx * 128;

  int srow = tid >> 3;                     // 0..63
  int scolb = (tid & 7) << 4;              // 0..112 step16
  int ssw = scolb ^ ((srow & 7) << 4);     // pre-swizzled source column (bytes)
  const char* Agp = (const char*)A  + (size_t)(m0 + srow) * 2048 + ssw;
  const char* Bgp = (const char*)Bt + (size_t)(n0 + srow) * 2048 + ssw;

  // stage all 6 units (A:4, B:2) of K-tile t_ into buffer (t_%3)
  #define STAGE6(t_) { int bb_ = (t_)%3; \
    char* ab_ = smem + bb_*32768 + (wave<<10); \
    const char* ag_ = Agp + (size_t)(t_)*128; \
    gload_lds16(ag_,          ab_); \
    gload_lds16(ag_+131072,   ab_+8192); \
    gload_lds16(ag_+262144,   ab_+16384); \
    gload_lds16(ag_+393216,   ab_+24576); \
    char* bbp_ = smem + 98304 + bb_*16384 + (wave<<10); \
    const char* bg_ = Bgp + (size_t)(t_)*128; \
    gload_lds16(bg_,          bbp_); \
    gload_lds16(bg_+131072,   bbp_+8192); }

  f32x4 acc[4][4];
  #pragma unroll
  for (int i=0;i<4;i++)
    #pragma unroll
    for (int j=0;j<4;j++) acc[i][j] = (f32x4){0.f,0.f,0.f,0.f};

  // prologue: tiles 0 and 1 in flight; confirm 0, barrier
  STAGE6(0);
  STAGE6(1);
  asm volatile("s_waitcnt vmcnt(6)" ::: "memory");   // tile 0 landed
  BARRIER(); CFENCE();

  for (int t=0; t<nkt; ++t){
    // stage t+2, counted wait confirms t+1 (consumed next iter)
    if (t+2 < nkt){
      STAGE6(t+2);
      asm volatile("s_waitcnt vmcnt(6)" ::: "memory");
    } else {
      asm volatile("s_waitcnt vmcnt(0)" ::: "memory");
    }
    const char* Asb = smem + (t%3)*32768;
    const char* Bsb = smem + 98304 + (t%3)*16384;
    short8 a[4][2], bq[4][2];
    #pragma unroll
    for (int i=0;i<4;i++){
      int row = wm*64 + i*16 + cl;
      #pragma unroll
      for (int ks=0;ks<2;ks++)
        a[i][ks] = *(const short8*)(Asb + row*128 + ((ks*64 + g*16) ^ ((row&7)<<4)));
    }
    #pragma unroll
    for (int j=0;j<4;j++){
      int row = wn*64 + j*16 + cl;
      #pragma unroll
      for (int ks=0;ks<2;ks++)
        bq[j][ks] = *(const short8*)(Bsb + row*128 + ((ks*64 + g*16) ^ ((row&7)<<4)));
    }
    __builtin_amdgcn_s_setprio(1);
    #pragma unroll
    for (int ks=0;ks<2;ks++)
      #pragma unroll
      for (int i=0;i<4;i++)
        #pragma unroll
        for (int j=0;j<4;j++)
          acc[i][j] = __builtin_amdgcn_mfma_f32_16x16x32_bf16(a[i][ks], bq[j][ks], acc[i][j], 0, 0, 0);
    __builtin_amdgcn_s_setprio(0);
    CFENCE(); BARRIER(); CFENCE();
  }
  #undef STAGE6

  // epilogue: D frag layout col=lane&15, row=4*(lane>>4)+reg
  #pragma unroll
  for (int jj=0;jj<4;jj++){
    int col = n0 + wn*64 + jj*16 + cl;
    float bj = bias[col];
    if (MODE == 0){
      #pragma unroll
      for (int i=0;i<4;i++){
        int rowb = m0 + wm*64 + i*16 + g*4;
        #pragma unroll
        for (int r=0;r<4;r++)
          ((float*)Cout)[(size_t)(rowb+r)*Nn_ + col] = acc[i][jj][r] + bj;
      }
    } else if (col < 2*Cn){
      // Q,K region: row-major bf16 qkv
      #pragma unroll
      for (int i=0;i<4;i++){
        int rowb = m0 + wm*64 + i*16 + g*4;
        #pragma unroll
        for (int r=0;r<4;r++)
          ((u16*)Cout)[(size_t)(rowb+r)*Nn_ + col] = f2bf(acc[i][jj][r] + bj);
      }
    } else {
      // V region: store transposed into vt[bh][d][t] (4 tokens -> uint2)
      int hd = col - 2*Cn;                 // h*64 + d
      #pragma unroll
      for (int i=0;i<4;i++){
        int rowb = m0 + wm*64 + i*16 + g*4;
        int bb = rowb >> 11, tt = rowb & 2047;
        u16* dst = vt + (((size_t)(bb*16 + (hd>>6)))*64 + (hd&63))*2048 + tt;
        uint2 pk;
        pk.x = (u32)f2bf(acc[i][jj][0]+bj) | ((u32)f2bf(acc[i][jj][1]+bj) << 16);
        pk.y = (u32)f2bf(acc[i][jj][2]+bj) | ((u32)f2bf(acc[i][jj][3]+bj) << 16);
        *(uint2*)dst = pk;
      }
    }
  }
}

// ---------------- causal flash attention, 32x32 swapped-QK^T ----------------
// grid 1024: blk -> (xcd, bh, qt) heavy-first; 4 blocks/CU.
__global__ __launch_bounds__(256, 4)
void k_attn(const u16* __restrict__ qkv, const u16* __restrict__ vt, u16* __restrict__ yb){
  __shared__ __align__(16) u16 Ks[2][64*64];
  __shared__ __align__(16) u16 Vs[2][64*64];
  int tid = threadIdx.x, wave = tid >> 6, lane = tid & 63;
  int ql = lane & 31, hi = lane >> 5;
  int blk = blockIdx.x;
  int xcd = blk & 7, rest = blk >> 3;
  int bh  = xcd + 8*(rest & 7);
  int qt  = 15 - (rest >> 3);
  int b = bh >> 4, h = bh & 15;

  const u16* Kbase = qkv + (size_t)b*Tn*N1n + Cn + h*HSn;
  const u16* Vbase = vt  + (size_t)bh*HSn*Tn;

  auto STAGE = [&](int bufi, int kt){
    int kb_ = kt*64;
    #pragma unroll
    for (int it=0; it<2; ++it){
      int off = it*4096 + tid*16;
      int row = off >> 7;
      int cb  = off & 127;
      int gc  = (cb ^ ((row & 7) << 4)) >> 1;
      gload_lds16(Kbase + (size_t)(kb_ + row)*N1n + gc,
                  (char*)&Ks[bufi][0] + it*4096 + (wave << 10));
      gload_lds16(Vbase + (size_t)row*Tn + kb_ + gc,
                  (char*)&Vs[bufi][0] + it*4096 + (wave << 10));
    }
  };

  const float QSC = 0.125f * 1.44269504f;

  int q0 = qt * 128;
  int qw0 = q0 + wave*32;
  int qg  = qw0 + ql;
  int ntiles = 2*qt + 2;

  const u16* Qp = qkv + (size_t)(b*Tn + qg)*N1n + h*HSn;
  short8 qf[4];
  #pragma unroll
  for (int dc=0; dc<4; ++dc){
    union { short8 v; u32 w[4]; } qa;
    qa.v = *(const short8*)&Qp[dc*16 + hi*8];
    #pragma unroll
    for (int t=0; t<4; ++t){
      u32 w = qa.w[t];
      float lo = __uint_as_float(w << 16);
      float hf = __uint_as_float(w & 0xffff0000u);
      qa.w[t] = pkbf(lo*QSC, hf*QSC);
    }
    qf[dc] = qa.v;
  }

  f32x16 accO[2];
  #pragma unroll
  for (int f=0; f<2; ++f)
    #pragma unroll
    for (int r=0; r<16; ++r) accO[f][r] = 0.f;
  float m_ = -1e30f, l_ = 0.f;

  STAGE(0, 0);
  asm volatile("s_waitcnt vmcnt(0)" ::: "memory");
  __syncthreads();
  int buf = 0;

  for (int kt=0; kt<ntiles; ++kt){
    if (kt+1 < ntiles) STAGE(buf^1, kt+1);
    const char* Ksb = (const char*)&Ks[buf][0];
    const char* Vsb = (const char*)&Vs[buf][0];
    #pragma unroll
    for (int ksub=0; ksub<2; ++ksub){
      int kbase = kt*64 + ksub*32;
      if (kbase <= qw0 + 31){
        f32x16 s;
        #pragma unroll
        for (int r=0; r<16; ++r) s[r] = 0.f;
        __builtin_amdgcn_s_setprio(1);
        #pragma unroll
        for (int dc=0; dc<4; ++dc){
          short8 kf = *(const short8*)(Ksb + ((ksub*32 + ql) << 7)
                          + ((dc*32 + hi*16) ^ ((ql & 7) << 4)));
          s = __builtin_amdgcn_mfma_f32_32x32x16_bf16(kf, qf[dc], s, 0, 0, 0);
        }
        __builtin_amdgcn_s_setprio(0);
        float p[16];
        if (kbase + 31 > qw0){
          #pragma unroll
          for (int r=0; r<16; ++r){
            int krow = kbase + (r&3) + 8*(r>>2) + 4*hi;
            p[r] = (krow > qg) ? -1e30f : s[r];
          }
        } else {
          #pragma unroll
          for (int r=0; r<16; ++r) p[r] = s[r];
        }
        float t0 = fmaxf(fmaxf(fmaxf(p[0],p[1]),fmaxf(p[2],p[3])),
                         fmaxf(fmaxf(p[4],p[5]),fmaxf(p[6],p[7])));
        float t1 = fmaxf(fmaxf(fmaxf(p[8],p[9]),fmaxf(p[10],p[11])),
                         fmaxf(fmaxf(p[12],p[13]),fmaxf(p[14],p[15])));
        float tm = fmaxf(t0, t1);
        { u32 ua = __float_as_uint(tm), ub = ua; plswap(ua, ub);
          tm = fmaxf(__uint_as_float(ua), __uint_as_float(ub)); }
        if (!__all(tm - m_ <= 8.0f)){
          float mn = fmaxf(m_, tm);
          float al = fexp2(m_ - mn);
          m_ = mn; l_ *= al;
          #pragma unroll
          for (int f=0; f<2; ++f)
            #pragma unroll
            for (int r=0; r<16; ++r) accO[f][r] *= al;
        }
        float ls = 0.f;
        #pragma unroll
        for (int r=0; r<16; ++r){ float e = fexp2(p[r] - m_); p[r] = e; ls += e; }
        { u32 ua = __float_as_uint(ls), ub = ua; plswap(ua, ub);
          l_ += __uint_as_float(ua) + __uint_as_float(ub); }
        #pragma unroll
        for (int ks=0; ks<2; ++ks){
          int pb = ks*8;
          u32 w0 = pkbf(p[pb+0], p[pb+1]);
          u32 w1 = pkbf(p[pb+2], p[pb+3]);
          u32 w2 = pkbf(p[pb+4], p[pb+5]);
          u32 w3 = pkbf(p[pb+6], p[pb+7]);
          plswap(w0, w2);
          plswap(w1, w3);
          union { u32 w[4]; short8 v; } pu;
          pu.w[0] = w0; pu.w[1] = w1; pu.w[2] = w2; pu.w[3] = w3;
          __builtin_amdgcn_s_setprio(1);
          #pragma unroll
          for (int f=0; f<2; ++f){
            short8 vf = *(const short8*)(Vsb + ((f*32 + ql) << 7)
                            + ((ksub*64 + ks*32 + hi*16) ^ ((ql & 7) << 4)));
            accO[f] = __builtin_amdgcn_mfma_f32_32x32x16_bf16(vf, pu.v, accO[f], 0, 0, 0);
          }
          __builtin_amdgcn_s_setprio(0);
        }
      }
    }
    asm volatile("s_waitcnt vmcnt(0)" ::: "memory");
    __syncthreads();
    buf ^= 1;
  }

  float rl = 1.0f / l_;
  u16* yp = yb + (size_t)(b*Tn + qg)*Cn + h*HSn;
  #pragma unroll
  for (int f=0; f<2; ++f)
    #pragma unroll
    for (int rq=0; rq<4; ++rq){
      int d0 = f*32 + rq*8 + hi*4;
      float v0 = accO[f][rq*4+0]*rl, v1 = accO[f][rq*4+1]*rl;
      float v2 = accO[f][rq*4+2]*rl, v3 = accO[f][rq*4+3]*rl;
      uint2 pk2;
      pk2.x = (u32)f2bf(v0) | ((u32)f2bf(v1) << 16);
      pk2.y = (u32)f2bf(v2) | ((u32)f2bf(v3) << 16);
      *(uint2*)&yp[d0] = pk2;
    }
}

extern "C" void kernel_launch(void* const* d_in, const int* in_sizes, int n_in,
                              void* d_out, int out_size, void* d_ws, size_t ws_size,
                              hipStream_t stream)
{
  const float* x      = (const float*)d_in[0];
  const float* w_attn = (const float*)d_in[1];
  const float* b_attn = (const float*)d_in[2];
  const float* w_proj = (const float*)d_in[3];
  const float* b_proj = (const float*)d_in[4];
  float* out = (float*)d_out;
  char* ws = (char*)d_ws;

  size_t off = 0;
  u16* xb  = (u16*)(ws + off); off += (size_t)Mn*Cn*2;
  u16* waT = (u16*)(ws + off); off += (size_t)N1n*Cn*2;
  u16* wpT = (u16*)(ws + off); off += (size_t)Cn*Cn*2;
  u16* qkv = (u16*)(ws + off); off += (size_t)Mn*N1n*2;
  u16* vt  = (u16*)(ws + off); off += (size_t)Bn*Hn*HSn*Tn*2;
  u16* yb  = (u16*)(ws + off); off += (size_t)Mn*Cn*2;

  (void)hipFuncSetAttribute((const void*)k_gemm1p<1>,
        hipFuncAttributeMaxDynamicSharedMemorySize, 147456);
  (void)hipFuncSetAttribute((const void*)k_gemm1p<0>,
        hipFuncAttributeMaxDynamicSharedMemorySize, 147456);

  k_cvt<<<dim3(Mn*Cn/8/256), 256, 0, stream>>>(x, xb, Mn*Cn/8);
  k_tcvt<<<dim3(N1n/64, Cn/64), 256, 0, stream>>>(w_attn, waT, Cn, N1n);
  k_tcvt<<<dim3(Cn/64, Cn/64), 256, 0, stream>>>(w_proj, wpT, Cn, Cn);
  k_gemm1p<1><<<dim3((Mn/256)*(N1n/128)), 512, 147456, stream>>>(xb, waT, b_attn, qkv, vt, N1n);
  k_attn<<<dim3(1024), 256, 0, stream>>>(qkv, vt, yb);
  k_gemm1p<0><<<dim3((Mn/256)*(Cn/128)), 512, 147456, stream>>>(yb, wpT, b_proj, out, nullptr, Cn);
}

// Round 7
// 148.758 us; speedup vs baseline: 3.8159x; 1.0535x over previous
//
#include <hip/hip_runtime.h>
#include <stdint.h>

#define Bn 4
#define Tn 2048
#define Cn 1024
#define Hn 16
#define HSn 64
#define Mn (Bn*Tn)
#define N1n (3*Cn)

typedef unsigned short u16;
typedef unsigned int u32;
typedef __attribute__((ext_vector_type(8))) short short8;
typedef __attribute__((ext_vector_type(4))) float f32x4;
typedef __attribute__((ext_vector_type(16))) float f32x16;

__device__ __forceinline__ u16 f2bf(float f){
  u32 u = __float_as_uint(f);
  u += 0x7fffu + ((u >> 16) & 1u);
  return (u16)(u >> 16);
}

__device__ __forceinline__ u32 pkbf(float lo, float hi_){
  u32 r; asm("v_cvt_pk_bf16_f32 %0, %1, %2" : "=v"(r) : "v"(lo), "v"(hi_)); return r;
}

__device__ __forceinline__ float fexp2(float x){
  float r; asm("v_exp_f32 %0, %1" : "=v"(r) : "v"(x)); return r;
}

__device__ __forceinline__ void plswap(u32 &a, u32 &b){
  auto r = __builtin_amdgcn_permlane32_swap(a, b, false, false);
  a = r[0]; b = r[1];
}

__device__ __forceinline__ void gload_lds16(const void* g, void* l){
  __builtin_amdgcn_global_load_lds(
      (const __attribute__((address_space(1))) u32*)g,
      (__attribute__((address_space(3))) u32*)l, 16, 0, 0);
}

#define BARRIER() __builtin_amdgcn_s_barrier()
#define CFENCE() asm volatile("" ::: "memory")

// ---------------- flat f32 -> bf16 convert ----------------
__global__ void k_cvt(const float* __restrict__ in, u16* __restrict__ out, int n8){
  int i = blockIdx.x*256 + threadIdx.x;
  if (i >= n8) return;
  const float4* p = (const float4*)(in) + (size_t)i*2;
  float4 a = p[0], b = p[1];
  uint4 r;
  r.x = (u32)f2bf(a.x) | ((u32)f2bf(a.y) << 16);
  r.y = (u32)f2bf(a.z) | ((u32)f2bf(a.w) << 16);
  r.z = (u32)f2bf(b.x) | ((u32)f2bf(b.y) << 16);
  r.w = (u32)f2bf(b.z) | ((u32)f2bf(b.w) << 16);
  *((uint4*)(out) + i) = r;
}

// ------- transpose + convert: in f32 [R][Cc] -> out bf16 [Cc][R] -------
__global__ void k_tcvt(const float* __restrict__ in, u16* __restrict__ out, int R, int Cc){
  __shared__ float sh[64][68];
  int tid = threadIdx.x;
  int c0 = blockIdx.x*64, r0 = blockIdx.y*64;
  int rr = tid >> 4, c4 = (tid & 15) * 4;
  #pragma unroll
  for (int p=0;p<4;p++){
    int r = rr + 16*p;
    *(float4*)&sh[r][c4] = *(const float4*)&in[(size_t)(r0+r)*Cc + c0 + c4];
  }
  __syncthreads();
  #pragma unroll
  for (int p=0;p<4;p++){
    int oc = rr + 16*p;
    u32 w0 = (u32)f2bf(sh[c4+0][oc]) | ((u32)f2bf(sh[c4+1][oc]) << 16);
    u32 w1 = (u32)f2bf(sh[c4+2][oc]) | ((u32)f2bf(sh[c4+3][oc]) << 16);
    uint2 pk; pk.x = w0; pk.y = w1;
    *(uint2*)&out[(size_t)(c0+oc)*R + r0 + c4] = pk;
  }
}

// ---- 128x128 counted-vmcnt GEMM: C = A . Bt^T + bias ----
// A [M][1024] bf16, Bt [N][1024] bf16. Tile 128x128, BK=64, 4 waves (2x2),
// per-wave 64x64. Double-buffered 64KB dyn LDS, 2 blocks/CU (cross-block TLP
// hides LDS/HBM under MFMA). vmcnt(8) counted, raw barriers, no drain.
// MODE1: bf16 out + V-cols (>=2C) transposed into vt. MODE0: f32 out.
template <int MODE>
__global__ __launch_bounds__(256, 2)
void k_gemm2(const u16* __restrict__ A, const u16* __restrict__ Bt,
             const float* __restrict__ bias, void* __restrict__ Cout,
             u16* __restrict__ vt, int Nn_, int byPerXcd)
{
  extern __shared__ char smem[];           // [2][A 16KB | B 16KB] = 64KB
  const int nkt = 16;                      // K=1024/64
  int tid = threadIdx.x;
  int wave = tid >> 6, lane = tid & 63, g = lane >> 4, cl = lane & 15;
  int wm = wave >> 1, wn = wave & 1;

  // per-XCD chunk: 8 consecutive by-rows, column-major within chunk
  int xcd = blockIdx.x & 7, idx = blockIdx.x >> 3;
  int by = xcd * byPerXcd + (idx % byPerXcd);
  int bx = idx / byPerXcd;
  int m0 = by * 128, n0 = bx * 128;

  int srow = tid >> 3;                     // 0..31
  int scolb = (tid & 7) << 4;              // 0..112
  int ssw = scolb ^ ((srow & 7) << 4);     // pre-swizzled source column
  const char* Agp = (const char*)A  + (size_t)(m0 + srow) * 2048 + ssw;
  const char* Bgp = (const char*)Bt + (size_t)(n0 + srow) * 2048 + ssw;

  // stage K-tile t_ (A 16KB + B 16KB, 8 gloads/thread) into buffer b_
  #define STG(t_, b_) { \
    const char* ag = Agp + (size_t)(t_)*128; \
    const char* bg = Bgp + (size_t)(t_)*128; \
    char* ab = smem + (b_)*32768 + (wave<<10); \
    char* bb = ab + 16384; \
    gload_lds16(ag,          ab); \
    gload_lds16(ag+ 65536,   ab+4096); \
    gload_lds16(ag+131072,   ab+8192); \
    gload_lds16(ag+196608,   ab+12288); \
    gload_lds16(bg,          bb); \
    gload_lds16(bg+ 65536,   bb+4096); \
    gload_lds16(bg+131072,   bb+8192); \
    gload_lds16(bg+196608,   bb+12288); }

  f32x4 acc[4][4];
  #pragma unroll
  for (int i=0;i<4;i++)
    #pragma unroll
    for (int j=0;j<4;j++) acc[i][j] = (f32x4){0.f,0.f,0.f,0.f};

  STG(0, 0);

  for (int t=0; t<nkt; ++t){
    int b = t & 1;
    if (t+1 < nkt){
      STG(t+1, b^1);                               // WAR-safe: trailing barrier of t-1
      asm volatile("s_waitcnt vmcnt(8)" ::: "memory");  // tile t landed (this wave)
    } else {
      asm volatile("s_waitcnt vmcnt(0)" ::: "memory");
    }
    BARRIER(); CFENCE();                           // all waves' tile-t parts landed
    const char* Asb = smem + b*32768;
    const char* Bsb = Asb + 16384;
    short8 a[4][2], bq[4][2];
    #pragma unroll
    for (int i=0;i<4;i++){
      int row = wm*64 + i*16 + cl;
      #pragma unroll
      for (int ks=0;ks<2;ks++)
        a[i][ks] = *(const short8*)(Asb + row*128 + ((ks*64 + g*16) ^ ((row&7)<<4)));
    }
    #pragma unroll
    for (int j=0;j<4;j++){
      int row = wn*64 + j*16 + cl;
      #pragma unroll
      for (int ks=0;ks<2;ks++)
        bq[j][ks] = *(const short8*)(Bsb + row*128 + ((ks*64 + g*16) ^ ((row&7)<<4)));
    }
    asm volatile("s_waitcnt lgkmcnt(0)" ::: "memory");
    __builtin_amdgcn_s_setprio(1);
    #pragma unroll
    for (int ks=0;ks<2;ks++)
      #pragma unroll
      for (int i=0;i<4;i++)
        #pragma unroll
        for (int j=0;j<4;j++)
          acc[i][j] = __builtin_amdgcn_mfma_f32_16x16x32_bf16(a[i][ks], bq[j][ks], acc[i][j], 0, 0, 0);
    __builtin_amdgcn_s_setprio(0);
    CFENCE(); BARRIER(); CFENCE();                 // reads of buf b done -> next STG may overwrite
  }
  #undef STG

  // epilogue: D frag layout col=lane&15, row=4*(lane>>4)+reg
  #pragma unroll
  for (int jj=0;jj<4;jj++){
    int col = n0 + wn*64 + jj*16 + cl;
    float bj = bias[col];
    if (MODE == 0){
      #pragma unroll
      for (int i=0;i<4;i++){
        int rowb = m0 + wm*64 + i*16 + g*4;
        #pragma unroll
        for (int r=0;r<4;r++)
          ((float*)Cout)[(size_t)(rowb+r)*Nn_ + col] = acc[i][jj][r] + bj;
      }
    } else if (col < 2*Cn){
      #pragma unroll
      for (int i=0;i<4;i++){
        int rowb = m0 + wm*64 + i*16 + g*4;
        #pragma unroll
        for (int r=0;r<4;r++)
          ((u16*)Cout)[(size_t)(rowb+r)*Nn_ + col] = f2bf(acc[i][jj][r] + bj);
      }
    } else {
      // V region: store transposed into vt[bh][d][t]
      int hd = col - 2*Cn;
      #pragma unroll
      for (int i=0;i<4;i++){
        int rowb = m0 + wm*64 + i*16 + g*4;
        int bb = rowb >> 11, tt = rowb & 2047;
        u16* dst = vt + (((size_t)(bb*16 + (hd>>6)))*64 + (hd&63))*2048 + tt;
        uint2 pk;
        pk.x = (u32)f2bf(acc[i][jj][0]+bj) | ((u32)f2bf(acc[i][jj][1]+bj) << 16);
        pk.y = (u32)f2bf(acc[i][jj][2]+bj) | ((u32)f2bf(acc[i][jj][3]+bj) << 16);
        *(uint2*)dst = pk;
      }
    }
  }
}

// ---------------- causal flash attention, 32x32 swapped-QK^T ----------------
// grid 1024: blk -> (xcd, bh, qt) heavy-first; 4 blocks/CU.
__global__ __launch_bounds__(256, 4)
void k_attn(const u16* __restrict__ qkv, const u16* __restrict__ vt, u16* __restrict__ yb){
  __shared__ __align__(16) u16 Ks[2][64*64];
  __shared__ __align__(16) u16 Vs[2][64*64];
  int tid = threadIdx.x, wave = tid >> 6, lane = tid & 63;
  int ql = lane & 31, hi = lane >> 5;
  int blk = blockIdx.x;
  int xcd = blk & 7, rest = blk >> 3;
  int bh  = xcd + 8*(rest & 7);
  int qt  = 15 - (rest >> 3);
  int b = bh >> 4, h = bh & 15;

  const u16* Kbase = qkv + (size_t)b*Tn*N1n + Cn + h*HSn;
  const u16* Vbase = vt  + (size_t)bh*HSn*Tn;

  auto STAGE = [&](int bufi, int kt){
    int kb_ = kt*64;
    #pragma unroll
    for (int it=0; it<2; ++it){
      int off = it*4096 + tid*16;
      int row = off >> 7;
      int cb  = off & 127;
      int gc  = (cb ^ ((row & 7) << 4)) >> 1;
      gload_lds16(Kbase + (size_t)(kb_ + row)*N1n + gc,
                  (char*)&Ks[bufi][0] + it*4096 + (wave << 10));
      gload_lds16(Vbase + (size_t)row*Tn + kb_ + gc,
                  (char*)&Vs[bufi][0] + it*4096 + (wave << 10));
    }
  };

  const float QSC = 0.125f * 1.44269504f;

  int q0 = qt * 128;
  int qw0 = q0 + wave*32;
  int qg  = qw0 + ql;
  int ntiles = 2*qt + 2;

  const u16* Qp = qkv + (size_t)(b*Tn + qg)*N1n + h*HSn;
  short8 qf[4];
  #pragma unroll
  for (int dc=0; dc<4; ++dc){
    union { short8 v; u32 w[4]; } qa;
    qa.v = *(const short8*)&Qp[dc*16 + hi*8];
    #pragma unroll
    for (int t=0; t<4; ++t){
      u32 w = qa.w[t];
      float lo = __uint_as_float(w << 16);
      float hf = __uint_as_float(w & 0xffff0000u);
      qa.w[t] = pkbf(lo*QSC, hf*QSC);
    }
    qf[dc] = qa.v;
  }

  f32x16 accO[2];
  #pragma unroll
  for (int f=0; f<2; ++f)
    #pragma unroll
    for (int r=0; r<16; ++r) accO[f][r] = 0.f;
  float m_ = -1e30f, l_ = 0.f;

  STAGE(0, 0);
  asm volatile("s_waitcnt vmcnt(0)" ::: "memory");
  __syncthreads();
  int buf = 0;

  for (int kt=0; kt<ntiles; ++kt){
    if (kt+1 < ntiles) STAGE(buf^1, kt+1);
    const char* Ksb = (const char*)&Ks[buf][0];
    const char* Vsb = (const char*)&Vs[buf][0];
    #pragma unroll
    for (int ksub=0; ksub<2; ++ksub){
      int kbase = kt*64 + ksub*32;
      if (kbase <= qw0 + 31){
        f32x16 s;
        #pragma unroll
        for (int r=0; r<16; ++r) s[r] = 0.f;
        __builtin_amdgcn_s_setprio(1);
        #pragma unroll
        for (int dc=0; dc<4; ++dc){
          short8 kf = *(const short8*)(Ksb + ((ksub*32 + ql) << 7)
                          + ((dc*32 + hi*16) ^ ((ql & 7) << 4)));
          s = __builtin_amdgcn_mfma_f32_32x32x16_bf16(kf, qf[dc], s, 0, 0, 0);
        }
        __builtin_amdgcn_s_setprio(0);
        float p[16];
        if (kbase + 31 > qw0){
          #pragma unroll
          for (int r=0; r<16; ++r){
            int krow = kbase + (r&3) + 8*(r>>2) + 4*hi;
            p[r] = (krow > qg) ? -1e30f : s[r];
          }
        } else {
          #pragma unroll
          for (int r=0; r<16; ++r) p[r] = s[r];
        }
        float t0 = fmaxf(fmaxf(fmaxf(p[0],p[1]),fmaxf(p[2],p[3])),
                         fmaxf(fmaxf(p[4],p[5]),fmaxf(p[6],p[7])));
        float t1 = fmaxf(fmaxf(fmaxf(p[8],p[9]),fmaxf(p[10],p[11])),
                         fmaxf(fmaxf(p[12],p[13]),fmaxf(p[14],p[15])));
        float tm = fmaxf(t0, t1);
        { u32 ua = __float_as_uint(tm), ub = ua; plswap(ua, ub);
          tm = fmaxf(__uint_as_float(ua), __uint_as_float(ub)); }
        if (!__all(tm - m_ <= 8.0f)){
          float mn = fmaxf(m_, tm);
          float al = fexp2(m_ - mn);
          m_ = mn; l_ *= al;
          #pragma unroll
          for (int f=0; f<2; ++f)
            #pragma unroll
            for (int r=0; r<16; ++r) accO[f][r] *= al;
        }
        float ls = 0.f;
        #pragma unroll
        for (int r=0; r<16; ++r){ float e = fexp2(p[r] - m_); p[r] = e; ls += e; }
        { u32 ua = __float_as_uint(ls), ub = ua; plswap(ua, ub);
          l_ += __uint_as_float(ua) + __uint_as_float(ub); }
        #pragma unroll
        for (int ks=0; ks<2; ++ks){
          int pb = ks*8;
          u32 w0 = pkbf(p[pb+0], p[pb+1]);
          u32 w1 = pkbf(p[pb+2], p[pb+3]);
          u32 w2 = pkbf(p[pb+4], p[pb+5]);
          u32 w3 = pkbf(p[pb+6], p[pb+7]);
          plswap(w0, w2);
          plswap(w1, w3);
          union { u32 w[4]; short8 v; } pu;
          pu.w[0] = w0; pu.w[1] = w1; pu.w[2] = w2; pu.w[3] = w3;
          __builtin_amdgcn_s_setprio(1);
          #pragma unroll
          for (int f=0; f<2; ++f){
            short8 vf = *(const short8*)(Vsb + ((f*32 + ql) << 7)
                            + ((ksub*64 + ks*32 + hi*16) ^ ((ql & 7) << 4)));
            accO[f] = __builtin_amdgcn_mfma_f32_32x32x16_bf16(vf, pu.v, accO[f], 0, 0, 0);
          }
          __builtin_amdgcn_s_setprio(0);
        }
      }
    }
    asm volatile("s_waitcnt vmcnt(0)" ::: "memory");
    __syncthreads();
    buf ^= 1;
  }

  float rl = 1.0f / l_;
  u16* yp = yb + (size_t)(b*Tn + qg)*Cn + h*HSn;
  #pragma unroll
  for (int f=0; f<2; ++f)
    #pragma unroll
    for (int rq=0; rq<4; ++rq){
      int d0 = f*32 + rq*8 + hi*4;
      float v0 = accO[f][rq*4+0]*rl, v1 = accO[f][rq*4+1]*rl;
      float v2 = accO[f][rq*4+2]*rl, v3 = accO[f][rq*4+3]*rl;
      uint2 pk2;
      pk2.x = (u32)f2bf(v0) | ((u32)f2bf(v1) << 16);
      pk2.y = (u32)f2bf(v2) | ((u32)f2bf(v3) << 16);
      *(uint2*)&yp[d0] = pk2;
    }
}

extern "C" void kernel_launch(void* const* d_in, const int* in_sizes, int n_in,
                              void* d_out, int out_size, void* d_ws, size_t ws_size,
                              hipStream_t stream)
{
  const float* x      = (const float*)d_in[0];
  const float* w_attn = (const float*)d_in[1];
  const float* b_attn = (const float*)d_in[2];
  const float* w_proj = (const float*)d_in[3];
  const float* b_proj = (const float*)d_in[4];
  float* out = (float*)d_out;
  char* ws = (char*)d_ws;

  size_t off = 0;
  u16* xb  = (u16*)(ws + off); off += (size_t)Mn*Cn*2;
  u16* waT = (u16*)(ws + off); off += (size_t)N1n*Cn*2;
  u16* wpT = (u16*)(ws + off); off += (size_t)Cn*Cn*2;
  u16* qkv = (u16*)(ws + off); off += (size_t)Mn*N1n*2;
  u16* vt  = (u16*)(ws + off); off += (size_t)Bn*Hn*HSn*Tn*2;
  u16* yb  = (u16*)(ws + off); off += (size_t)Mn*Cn*2;

  (void)hipFuncSetAttribute((const void*)k_gemm2<1>,
        hipFuncAttributeMaxDynamicSharedMemorySize, 65536);
  (void)hipFuncSetAttribute((const void*)k_gemm2<0>,
        hipFuncAttributeMaxDynamicSharedMemorySize, 65536);

  k_cvt<<<dim3(Mn*Cn/8/256), 256, 0, stream>>>(x, xb, Mn*Cn/8);
  k_tcvt<<<dim3(N1n/64, Cn/64), 256, 0, stream>>>(w_attn, waT, Cn, N1n);
  k_tcvt<<<dim3(Cn/64, Cn/64), 256, 0, stream>>>(w_proj, wpT, Cn, Cn);
  // QKV: M/128=64 rows -> 8 per XCD; grid 64*24=1536
  k_gemm2<1><<<dim3((Mn/128)*(N1n/128)), 256, 65536, stream>>>(xb, waT, b_attn, qkv, vt, N1n, 8);
  k_attn<<<dim3(1024), 256, 0, stream>>>(qkv, vt, yb);
  // proj: grid 64*8=512
  k_gemm2<0><<<dim3((Mn/128)*(Cn/128)), 256, 65536, stream>>>(yb, wpT, b_proj, out, nullptr, Cn, 8);
}

// Round 8
// 142.405 us; speedup vs baseline: 3.9861x; 1.0446x over previous
//
#include <hip/hip_runtime.h>
#include <stdint.h>

#define Bn 4
#define Tn 2048
#define Cn 1024
#define Hn 16
#define HSn 64
#define Mn (Bn*Tn)
#define N1n (3*Cn)

typedef unsigned short u16;
typedef unsigned int u32;
typedef __attribute__((ext_vector_type(8))) short short8;
typedef __attribute__((ext_vector_type(4))) float f32x4;
typedef __attribute__((ext_vector_type(16))) float f32x16;

#define QSCf (0.125f * 1.44269504f)

__device__ __forceinline__ u16 f2bf(float f){
  u32 u = __float_as_uint(f);
  u += 0x7fffu + ((u >> 16) & 1u);
  return (u16)(u >> 16);
}

__device__ __forceinline__ u32 pkbf(float lo, float hi_){
  u32 r; asm("v_cvt_pk_bf16_f32 %0, %1, %2" : "=v"(r) : "v"(lo), "v"(hi_)); return r;
}

__device__ __forceinline__ float fexp2(float x){
  float r; asm("v_exp_f32 %0, %1" : "=v"(r) : "v"(x)); return r;
}

__device__ __forceinline__ float fmax3(float a, float b, float c){
  float r; asm("v_max3_f32 %0, %1, %2, %3" : "=v"(r) : "v"(a), "v"(b), "v"(c)); return r;
}

__device__ __forceinline__ void plswap(u32 &a, u32 &b){
  auto r = __builtin_amdgcn_permlane32_swap(a, b, false, false);
  a = r[0]; b = r[1];
}

__device__ __forceinline__ void gload_lds16(const void* g, void* l){
  __builtin_amdgcn_global_load_lds(
      (const __attribute__((address_space(1))) u32*)g,
      (__attribute__((address_space(3))) u32*)l, 16, 0, 0);
}

#define BARRIER() __builtin_amdgcn_s_barrier()
#define CFENCE() asm volatile("" ::: "memory")

// ---- fused pre-pass: x->bf16 | w_attn^T->bf16 | w_proj^T->bf16 ----
__device__ __forceinline__ void tcvt_body(const float* __restrict__ in,
                                          u16* __restrict__ out,
                                          int R, int Cc, int bxx, int byy,
                                          float sh[64][68]){
  int tid = threadIdx.x;
  int c0 = bxx*64, r0 = byy*64;
  int rr = tid >> 4, c4 = (tid & 15) * 4;
  #pragma unroll
  for (int p=0;p<4;p++){
    int r = rr + 16*p;
    *(float4*)&sh[r][c4] = *(const float4*)&in[(size_t)(r0+r)*Cc + c0 + c4];
  }
  __syncthreads();
  #pragma unroll
  for (int p=0;p<4;p++){
    int oc = rr + 16*p;
    u32 w0 = (u32)f2bf(sh[c4+0][oc]) | ((u32)f2bf(sh[c4+1][oc]) << 16);
    u32 w1 = (u32)f2bf(sh[c4+2][oc]) | ((u32)f2bf(sh[c4+3][oc]) << 16);
    uint2 pk; pk.x = w0; pk.y = w1;
    *(uint2*)&out[(size_t)(c0+oc)*R + r0 + c4] = pk;
  }
}

__global__ __launch_bounds__(256)
void k_pre(const float* __restrict__ x, const float* __restrict__ wa,
           const float* __restrict__ wp, u16* __restrict__ xb,
           u16* __restrict__ waT, u16* __restrict__ wpT){
  __shared__ float sh[64][68];
  int bid = blockIdx.x;
  if (bid < 4096){
    int i = bid*256 + threadIdx.x;           // n8 = Mn*Cn/8 = 1048576 = 4096*256
    const float4* p = (const float4*)(x) + (size_t)i*2;
    float4 a = p[0], b = p[1];
    uint4 r;
    r.x = (u32)f2bf(a.x) | ((u32)f2bf(a.y) << 16);
    r.y = (u32)f2bf(a.z) | ((u32)f2bf(a.w) << 16);
    r.z = (u32)f2bf(b.x) | ((u32)f2bf(b.y) << 16);
    r.w = (u32)f2bf(b.z) | ((u32)f2bf(b.w) << 16);
    *((uint4*)(xb) + i) = r;
  } else if (bid < 4096 + 768){
    int b2 = bid - 4096;                     // w_attn: [Cn][N1n] -> [N1n][Cn]
    tcvt_body(wa, waT, Cn, N1n, b2 % 48, b2 / 48, sh);
  } else {
    int b3 = bid - 4864;                     // w_proj: [Cn][Cn] -> [Cn][Cn]
    tcvt_body(wp, wpT, Cn, Cn, b3 % 16, b3 / 16, sh);
  }
}

// ---- 128x128 counted-vmcnt GEMM: C = A . Bt^T + bias ----
// MODE1: bf16 out; Q-cols (<C) pre-scaled by QSC; V-cols (>=2C) transposed
// into vt[bh][d][t]. MODE0: f32 out.
template <int MODE>
__global__ __launch_bounds__(256, 2)
void k_gemm2(const u16* __restrict__ A, const u16* __restrict__ Bt,
             const float* __restrict__ bias, void* __restrict__ Cout,
             u16* __restrict__ vt, int Nn_, int byPerXcd)
{
  extern __shared__ char smem[];           // [2][A 16KB | B 16KB] = 64KB
  const int nkt = 16;
  int tid = threadIdx.x;
  int wave = tid >> 6, lane = tid & 63, g = lane >> 4, cl = lane & 15;
  int wm = wave >> 1, wn = wave & 1;

  int xcd = blockIdx.x & 7, idx = blockIdx.x >> 3;
  int by = xcd * byPerXcd + (idx % byPerXcd);
  int bx = idx / byPerXcd;
  int m0 = by * 128, n0 = bx * 128;

  int srow = tid >> 3;
  int scolb = (tid & 7) << 4;
  int ssw = scolb ^ ((srow & 7) << 4);
  const char* Agp = (const char*)A  + (size_t)(m0 + srow) * 2048 + ssw;
  const char* Bgp = (const char*)Bt + (size_t)(n0 + srow) * 2048 + ssw;

  #define STG(t_, b_) { \
    const char* ag = Agp + (size_t)(t_)*128; \
    const char* bg = Bgp + (size_t)(t_)*128; \
    char* ab = smem + (b_)*32768 + (wave<<10); \
    char* bb = ab + 16384; \
    gload_lds16(ag,          ab); \
    gload_lds16(ag+ 65536,   ab+4096); \
    gload_lds16(ag+131072,   ab+8192); \
    gload_lds16(ag+196608,   ab+12288); \
    gload_lds16(bg,          bb); \
    gload_lds16(bg+ 65536,   bb+4096); \
    gload_lds16(bg+131072,   bb+8192); \
    gload_lds16(bg+196608,   bb+12288); }

  f32x4 acc[4][4];
  #pragma unroll
  for (int i=0;i<4;i++)
    #pragma unroll
    for (int j=0;j<4;j++) acc[i][j] = (f32x4){0.f,0.f,0.f,0.f};

  STG(0, 0);

  for (int t=0; t<nkt; ++t){
    int b = t & 1;
    if (t+1 < nkt){
      STG(t+1, b^1);
      asm volatile("s_waitcnt vmcnt(8)" ::: "memory");
    } else {
      asm volatile("s_waitcnt vmcnt(0)" ::: "memory");
    }
    BARRIER(); CFENCE();
    const char* Asb = smem + b*32768;
    const char* Bsb = Asb + 16384;
    short8 a[4][2], bq[4][2];
    #pragma unroll
    for (int i=0;i<4;i++){
      int row = wm*64 + i*16 + cl;
      #pragma unroll
      for (int ks=0;ks<2;ks++)
        a[i][ks] = *(const short8*)(Asb + row*128 + ((ks*64 + g*16) ^ ((row&7)<<4)));
    }
    #pragma unroll
    for (int j=0;j<4;j++){
      int row = wn*64 + j*16 + cl;
      #pragma unroll
      for (int ks=0;ks<2;ks++)
        bq[j][ks] = *(const short8*)(Bsb + row*128 + ((ks*64 + g*16) ^ ((row&7)<<4)));
    }
    asm volatile("s_waitcnt lgkmcnt(0)" ::: "memory");
    __builtin_amdgcn_s_setprio(1);
    #pragma unroll
    for (int ks=0;ks<2;ks++)
      #pragma unroll
      for (int i=0;i<4;i++)
        #pragma unroll
        for (int j=0;j<4;j++)
          acc[i][j] = __builtin_amdgcn_mfma_f32_16x16x32_bf16(a[i][ks], bq[j][ks], acc[i][j], 0, 0, 0);
    __builtin_amdgcn_s_setprio(0);
    CFENCE(); BARRIER(); CFENCE();
  }
  #undef STG

  #pragma unroll
  for (int jj=0;jj<4;jj++){
    int col = n0 + wn*64 + jj*16 + cl;
    float bj = bias[col];
    if (MODE == 0){
      #pragma unroll
      for (int i=0;i<4;i++){
        int rowb = m0 + wm*64 + i*16 + g*4;
        #pragma unroll
        for (int r=0;r<4;r++)
          ((float*)Cout)[(size_t)(rowb+r)*Nn_ + col] = acc[i][jj][r] + bj;
      }
    } else if (col < 2*Cn){
      float sc = (col < Cn) ? QSCf : 1.0f;   // pre-scale Q for exp2-domain attn
      #pragma unroll
      for (int i=0;i<4;i++){
        int rowb = m0 + wm*64 + i*16 + g*4;
        #pragma unroll
        for (int r=0;r<4;r++)
          ((u16*)Cout)[(size_t)(rowb+r)*Nn_ + col] = f2bf((acc[i][jj][r] + bj) * sc);
      }
    } else {
      int hd = col - 2*Cn;
      #pragma unroll
      for (int i=0;i<4;i++){
        int rowb = m0 + wm*64 + i*16 + g*4;
        int bb = rowb >> 11, tt = rowb & 2047;
        u16* dst = vt + (((size_t)(bb*16 + (hd>>6)))*64 + (hd&63))*2048 + tt;
        uint2 pk;
        pk.x = (u32)f2bf(acc[i][jj][0]+bj) | ((u32)f2bf(acc[i][jj][1]+bj) << 16);
        pk.y = (u32)f2bf(acc[i][jj][2]+bj) | ((u32)f2bf(acc[i][jj][3]+bj) << 16);
        *(uint2*)dst = pk;
      }
    }
  }
}

// ---------------- causal flash attention, 32x32 swapped-QK^T ----------------
// grid 1024: blk -> (xcd, bh, qt). qt chosen so each CU's 4 resident blocks
// sum to exactly 68 KV-tiles (balanced), heavy-first within each CU.
__global__ __launch_bounds__(256, 4)
void k_attn(const u16* __restrict__ qkv, const u16* __restrict__ vt, u16* __restrict__ yb){
  __shared__ __align__(16) u16 Ks[2][64*64];
  __shared__ __align__(16) u16 Vs[2][64*64];
  int tid = threadIdx.x, wave = tid >> 6, lane = tid & 63;
  int ql = lane & 31, hi = lane >> 5;
  int blk = blockIdx.x;
  int xcd = blk & 7, rest = blk >> 3;
  int bh  = xcd + 8*(rest & 7);
  int qtsel = rest >> 3;                  // 0..15
  int a_ = qtsel & 3, g_ = qtsel >> 2;
  int qt = (g_==0) ? (15 - a_) : (g_==1) ? (7 - a_) : (g_==2) ? (8 + a_) : a_;
  int b = bh >> 4, h = bh & 15;

  const u16* Kbase = qkv + (size_t)b*Tn*N1n + Cn + h*HSn;
  const u16* Vbase = vt  + (size_t)bh*HSn*Tn;

  auto STAGE = [&](int bufi, int kt){
    int kb_ = kt*64;
    #pragma unroll
    for (int it=0; it<2; ++it){
      int off = it*4096 + tid*16;
      int row = off >> 7;
      int cb  = off & 127;
      int gc  = (cb ^ ((row & 7) << 4)) >> 1;
      gload_lds16(Kbase + (size_t)(kb_ + row)*N1n + gc,
                  (char*)&Ks[bufi][0] + it*4096 + (wave << 10));
      gload_lds16(Vbase + (size_t)row*Tn + kb_ + gc,
                  (char*)&Vs[bufi][0] + it*4096 + (wave << 10));
    }
  };

  int q0 = qt * 128;
  int qw0 = q0 + wave*32;
  int qg  = qw0 + ql;
  int ntiles = 2*qt + 2;

  // Q B-frags: already pre-scaled by QSC in the QKV GEMM epilogue
  const u16* Qp = qkv + (size_t)(b*Tn + qg)*N1n + h*HSn;
  short8 qf[4];
  #pragma unroll
  for (int dc=0; dc<4; ++dc) qf[dc] = *(const short8*)&Qp[dc*16 + hi*8];

  f32x16 accO[2];
  #pragma unroll
  for (int f=0; f<2; ++f)
    #pragma unroll
    for (int r=0; r<16; ++r) accO[f][r] = 0.f;
  float m_ = -1e30f, l_ = 0.f;

  STAGE(0, 0);
  asm volatile("s_waitcnt vmcnt(0)" ::: "memory");
  __syncthreads();
  int buf = 0;

  for (int kt=0; kt<ntiles; ++kt){
    if (kt+1 < ntiles) STAGE(buf^1, kt+1);
    const char* Ksb = (const char*)&Ks[buf][0];
    const char* Vsb = (const char*)&Vs[buf][0];
    #pragma unroll
    for (int ksub=0; ksub<2; ++ksub){
      int kbase = kt*64 + ksub*32;
      if (kbase <= qw0 + 31){
        f32x16 s;
        #pragma unroll
        for (int r=0; r<16; ++r) s[r] = 0.f;
        __builtin_amdgcn_s_setprio(1);
        #pragma unroll
        for (int dc=0; dc<4; ++dc){
          short8 kf = *(const short8*)(Ksb + ((ksub*32 + ql) << 7)
                          + ((dc*32 + hi*16) ^ ((ql & 7) << 4)));
          s = __builtin_amdgcn_mfma_f32_32x32x16_bf16(kf, qf[dc], s, 0, 0, 0);
        }
        __builtin_amdgcn_s_setprio(0);
        float p[16];
        if (kbase + 31 > qw0){
          #pragma unroll
          for (int r=0; r<16; ++r){
            int krow = kbase + (r&3) + 8*(r>>2) + 4*hi;
            p[r] = (krow > qg) ? -1e30f : s[r];
          }
        } else {
          #pragma unroll
          for (int r=0; r<16; ++r) p[r] = s[r];
        }
        // ---- row max: max3 tree + permlane cross-half ----
        float r0 = fmax3(p[0], p[1], p[2]);
        float r1 = fmax3(p[3], p[4], p[5]);
        float r2 = fmax3(p[6], p[7], p[8]);
        float r3 = fmax3(p[9], p[10], p[11]);
        float r4 = fmax3(p[12], p[13], p[14]);
        float tm = fmaxf(fmax3(r0, r1, r2), fmax3(r3, r4, p[15]));
        { u32 ua = __float_as_uint(tm), ub = ua; plswap(ua, ub);
          tm = fmaxf(__uint_as_float(ua), __uint_as_float(ub)); }
        if (!__all(tm - m_ <= 8.0f)){
          float mn = fmaxf(m_, tm);
          float al = fexp2(m_ - mn);
          m_ = mn; l_ *= al;
          #pragma unroll
          for (int f=0; f<2; ++f)
            #pragma unroll
            for (int r=0; r<16; ++r) accO[f][r] *= al;
        }
        float ls = 0.f;
        #pragma unroll
        for (int r=0; r<16; ++r){ float e = fexp2(p[r] - m_); p[r] = e; ls += e; }
        { u32 ua = __float_as_uint(ls), ub = ua; plswap(ua, ub);
          l_ += __uint_as_float(ua) + __uint_as_float(ub); }
        // ---- P -> bf16 B-frags via permlane32_swap + PV ----
        #pragma unroll
        for (int ks=0; ks<2; ++ks){
          int pb = ks*8;
          u32 w0 = pkbf(p[pb+0], p[pb+1]);
          u32 w1 = pkbf(p[pb+2], p[pb+3]);
          u32 w2 = pkbf(p[pb+4], p[pb+5]);
          u32 w3 = pkbf(p[pb+6], p[pb+7]);
          plswap(w0, w2);
          plswap(w1, w3);
          union { u32 w[4]; short8 v; } pu;
          pu.w[0] = w0; pu.w[1] = w1; pu.w[2] = w2; pu.w[3] = w3;
          __builtin_amdgcn_s_setprio(1);
          #pragma unroll
          for (int f=0; f<2; ++f){
            short8 vf = *(const short8*)(Vsb + ((f*32 + ql) << 7)
                            + ((ksub*64 + ks*32 + hi*16) ^ ((ql & 7) << 4)));
            accO[f] = __builtin_amdgcn_mfma_f32_32x32x16_bf16(vf, pu.v, accO[f], 0, 0, 0);
          }
          __builtin_amdgcn_s_setprio(0);
        }
      }
    }
    asm volatile("s_waitcnt vmcnt(0)" ::: "memory");
    __syncthreads();
    buf ^= 1;
  }

  float rl = 1.0f / l_;
  u16* yp = yb + (size_t)(b*Tn + qg)*Cn + h*HSn;
  #pragma unroll
  for (int f=0; f<2; ++f)
    #pragma unroll
    for (int rq=0; rq<4; ++rq){
      int d0 = f*32 + rq*8 + hi*4;
      float v0 = accO[f][rq*4+0]*rl, v1 = accO[f][rq*4+1]*rl;
      float v2 = accO[f][rq*4+2]*rl, v3 = accO[f][rq*4+3]*rl;
      uint2 pk2;
      pk2.x = (u32)f2bf(v0) | ((u32)f2bf(v1) << 16);
      pk2.y = (u32)f2bf(v2) | ((u32)f2bf(v3) << 16);
      *(uint2*)&yp[d0] = pk2;
    }
}

extern "C" void kernel_launch(void* const* d_in, const int* in_sizes, int n_in,
                              void* d_out, int out_size, void* d_ws, size_t ws_size,
                              hipStream_t stream)
{
  const float* x      = (const float*)d_in[0];
  const float* w_attn = (const float*)d_in[1];
  const float* b_attn = (const float*)d_in[2];
  const float* w_proj = (const float*)d_in[3];
  const float* b_proj = (const float*)d_in[4];
  float* out = (float*)d_out;
  char* ws = (char*)d_ws;

  size_t off = 0;
  u16* xb  = (u16*)(ws + off); off += (size_t)Mn*Cn*2;
  u16* waT = (u16*)(ws + off); off += (size_t)N1n*Cn*2;
  u16* wpT = (u16*)(ws + off); off += (size_t)Cn*Cn*2;
  u16* qkv = (u16*)(ws + off); off += (size_t)Mn*N1n*2;
  u16* vt  = (u16*)(ws + off); off += (size_t)Bn*Hn*HSn*Tn*2;
  u16* yb  = (u16*)(ws + off); off += (size_t)Mn*Cn*2;

  (void)hipFuncSetAttribute((const void*)k_gemm2<1>,
        hipFuncAttributeMaxDynamicSharedMemorySize, 65536);
  (void)hipFuncSetAttribute((const void*)k_gemm2<0>,
        hipFuncAttributeMaxDynamicSharedMemorySize, 65536);

  k_pre<<<dim3(5120), 256, 0, stream>>>(x, w_attn, w_proj, xb, waT, wpT);
  k_gemm2<1><<<dim3((Mn/128)*(N1n/128)), 256, 65536, stream>>>(xb, waT, b_attn, qkv, vt, N1n, 8);
  k_attn<<<dim3(1024), 256, 0, stream>>>(qkv, vt, yb);
  k_gemm2<0><<<dim3((Mn/128)*(Cn/128)), 256, 65536, stream>>>(yb, wpT, b_proj, out, nullptr, Cn, 8);
}